// Round 11
// baseline (219.043 us; speedup 1.0000x reference)
//
#include <hip/hip_runtime.h>
#include <stdint.h>

#define SEQ 4096
#define EMB 768
#define HEADS 12
#define HD 64

typedef __attribute__((ext_vector_type(8))) short short8;
typedef __attribute__((ext_vector_type(4))) short short4v;
typedef __attribute__((ext_vector_type(8))) __bf16 bf16x8;
typedef __attribute__((ext_vector_type(4))) __bf16 bf16x4;
typedef __attribute__((ext_vector_type(4))) float f32x4;

// scale * log2(e) folded into Q: (1/sqrt(64)) * 1.4426950408889634
#define QSCALE 0.18033688011112043f

static __device__ __forceinline__ unsigned short f2bf(float f) {
    unsigned int u = __builtin_bit_cast(unsigned int, f);
    unsigned int r = 0x7fffu + ((u >> 16) & 1u);
    u += r;
    return (unsigned short)(u >> 16);
}

static __device__ __forceinline__ f32x4 mfma32(short8 a, short8 b, f32x4 c) {
    return __builtin_amdgcn_mfma_f32_16x16x32_bf16(
        __builtin_bit_cast(bf16x8, a), __builtin_bit_cast(bf16x8, b), c, 0, 0, 0);
}

static __device__ __forceinline__ f32x4 mfma16(short4v a, short4v b, f32x4 c) {
#if __has_builtin(__builtin_amdgcn_mfma_f32_16x16x16_bf16)
    return __builtin_amdgcn_mfma_f32_16x16x16_bf16(
        __builtin_bit_cast(bf16x4, a), __builtin_bit_cast(bf16x4, b), c, 0, 0, 0);
#else
    return __builtin_amdgcn_mfma_f32_16x16x16bf16_1k(a, b, c, 0, 0, 0);
#endif
}

static __device__ __forceinline__ short4v pack4bf(float a, float b, float c, float d) {
#if __has_builtin(__builtin_amdgcn_cvt_pk_bf16_f32)
    typedef __attribute__((ext_vector_type(2))) __bf16 bf16x2;
    bf16x2 lo = __builtin_amdgcn_cvt_pk_bf16_f32(a, b);
    bf16x2 hi = __builtin_amdgcn_cvt_pk_bf16_f32(c, d);
    uint2 u = {__builtin_bit_cast(unsigned int, lo), __builtin_bit_cast(unsigned int, hi)};
    return __builtin_bit_cast(short4v, u);
#else
    short4v p;
    p[0] = (short)f2bf(a); p[1] = (short)f2bf(b);
    p[2] = (short)f2bf(c); p[3] = (short)f2bf(d);
    return p;
#endif
}

// two float4 -> 8 bf16 packed in a uint4
static __device__ __forceinline__ uint4 pack8bf(float4 lo, float4 hi) {
    short4v a = pack4bf(lo.x, lo.y, lo.z, lo.w);
    short4v b = pack4bf(hi.x, hi.y, hi.z, hi.w);
    uint2 ua = __builtin_bit_cast(uint2, a), ub = __builtin_bit_cast(uint2, b);
    uint4 r;
    r.x = ua.x; r.y = ua.y; r.z = ub.x; r.w = ub.y;
    return r;
}

static __device__ __forceinline__ void load_lds16(const void* g, void* l) {
    __builtin_amdgcn_global_load_lds(
        (const __attribute__((address_space(1))) unsigned int*)(uintptr_t)g,
        (__attribute__((address_space(3))) unsigned int*)(uintptr_t)l, 16, 0, 0);
}

// partial-id for (h, i128, ch>=1); 36 slots/head, 432 total
static __device__ __forceinline__ int pid_of(int h, int i128, int ch) {
    int b = (i128 < 20) ? (i128 - 10)
                        : (i128 < 30 ? 10 + (i128 - 20) * 2 : 30 + (i128 - 30) * 3);
    return h * 36 + b + (ch - 1);
}

// online-softmax step over one 64-k tile held as st[4] (S^T layout).
static __device__ __forceinline__ void softmax_q(f32x4* st, float& m_i, float& l_i,
                                                 f32x4* O, short4v* pk) {
    float t0 = fmaxf(fmaxf(st[0][0], st[0][1]), fmaxf(st[0][2], st[0][3]));
    float t1 = fmaxf(fmaxf(st[1][0], st[1][1]), fmaxf(st[1][2], st[1][3]));
    float t2 = fmaxf(fmaxf(st[2][0], st[2][1]), fmaxf(st[2][2], st[2][3]));
    float t3 = fmaxf(fmaxf(st[3][0], st[3][1]), fmaxf(st[3][2], st[3][3]));
    float mx = fmaxf(fmaxf(t0, t1), fmaxf(t2, t3));  // this lane's 16 values
    if (__ballot(mx > m_i + 5.0f)) {  // rare after warm-up
        mx = fmaxf(mx, __shfl_xor(mx, 16));
        mx = fmaxf(mx, __shfl_xor(mx, 32));  // per-q (cross-quad) max
        const bool inc = mx > m_i;
        const float mn = inc ? mx : m_i;
        const float alpha = __builtin_amdgcn_exp2f(m_i - mn);
        m_i = mn;
        l_i *= alpha;
        for (int dt = 0; dt < 4; dt++)
            for (int r = 0; r < 4; r++) O[dt][r] *= alpha;
    }
    float rs = 0.f;
    for (int nt = 0; nt < 4; nt++) {
        float p0 = __builtin_amdgcn_exp2f(st[nt][0] - m_i);
        float p1 = __builtin_amdgcn_exp2f(st[nt][1] - m_i);
        float p2 = __builtin_amdgcn_exp2f(st[nt][2] - m_i);
        float p3 = __builtin_amdgcn_exp2f(st[nt][3] - m_i);
        rs += p0 + p1 + p2 + p3;
        pk[nt] = pack4bf(p0, p1, p2, p3);
    }
    l_i += rs;  // per-lane partial; reduced across quads at epilogue
}

// ---------------------------------------------------------------- woT convert
// R21: convert_all reduced to the wo transpose only (144 blocks). The x
// conversion and wq/wk/wv transposes are FUSED into gemm_qkv's staging
// (fp32 read -> cvt -> ds_write), eliminating the xb/wqkvT round-trips.
__global__ __launch_bounds__(256) void convert_wo(const float* __restrict__ wo,
                                                  unsigned short* __restrict__ woT) {
    __shared__ float Ls[64][65];
    const int idx = blockIdx.x;  // 0..143
    const int bx = idx / 12, by = idx % 12;
    const int k0 = bx * 64, n0 = by * 64;
    const int r = threadIdx.x >> 2, c0 = (threadIdx.x & 3) * 16;
    for (int j = 0; j < 16; j += 4) {
        float4 v = *(const float4*)&wo[(size_t)(k0 + r) * EMB + n0 + c0 + j];
        Ls[r][c0 + j] = v.x;
        Ls[r][c0 + j + 1] = v.y;
        Ls[r][c0 + j + 2] = v.z;
        Ls[r][c0 + j + 3] = v.w;
    }
    __syncthreads();
    unsigned short tmp[16];
    for (int j = 0; j < 16; j++) tmp[j] = f2bf(Ls[c0 + j][r]);
    *(uint4*)&woT[(size_t)(n0 + r) * EMB + k0 + c0] = *(uint4*)tmp;
    *(uint4*)&woT[(size_t)(n0 + r) * EMB + k0 + c0 + 8] = *(uint4*)(tmp + 8);
}

// ---------------------------------------------------------------- 64x128 QKV GEMM (fp32-fused)
// R21: stages A directly from x (fp32) and B directly from wq/wk/wv (fp32,
// transposed on the fly). Per K-step per thread: A = 2 float4 loads + 1 b128
// ds_write; B = 16 dword loads (n-contiguous per k -> coalesced) + 2 b128
// ds_writes. Write mappings keep every 16-lane phase contiguous (conflict-
// free): A row=tid>>2, col=(tid&3)*8; B row=tid>>1, kchunk=(tid&1)*16.
// Register prefetch across K-steps replaces the DMA; 1 barrier per K-step.
__global__ __launch_bounds__(256) void gemm_qkv(const float* __restrict__ x,
                                                const float* __restrict__ wq,
                                                const float* __restrict__ wk,
                                                const float* __restrict__ wv,
                                                const float* __restrict__ b0p,
                                                const float* __restrict__ b1p,
                                                const float* __restrict__ b2p,
                                                unsigned short* __restrict__ QKb,
                                                unsigned short* __restrict__ Vtb) {
    __shared__ __align__(16) unsigned short SMEM[12288];  // As[2]@0/2048 (64x32), Bs[2]@4096/8192 (128x32)
    const int tid = threadIdx.x;
    const int wave = tid >> 6, lane = tid & 63, quad = lane >> 4, l16 = lane & 15;
    const int m0 = blockIdx.x * 64, n0 = blockIdx.y * 128;
    const int z = blockIdx.y / 6;              // 0=Q, 1=K, 2=V (block-uniform)
    const int n0l = (blockIdx.y % 6) * 128;    // column offset within W
    const float* W = (z == 0) ? wq : (z == 1) ? wk : wv;
    const int wm = (wave >> 1) * 32, wn = (wave & 1) * 64;

    // staging thread mapping
    const int ar = tid >> 2, ac = (tid & 3) * 8;     // A: 64 rows x 4x8 cols
    const int bn = tid >> 1, bk0 = (tid & 1) * 16;   // B: 128 rows x 2x16 k
    const float* xrow = x + (size_t)(m0 + ar) * EMB;
    const float* wcol = W + n0l + bn;                // index: k*EMB + (n0l+bn)

    f32x4 acc[2][4] = {};

    float4 a0r, a1r;
    float brr[16];

    // ---- prologue: tile k0=0 -> regs -> buf0; tile k0=32 -> regs
    a0r = *(const float4*)&xrow[ac];
    a1r = *(const float4*)&xrow[ac + 4];
#pragma unroll
    for (int j = 0; j < 16; j++) brr[j] = wcol[(size_t)(bk0 + j) * EMB];
    {
        *(uint4*)&SMEM[ar * 32 + ac] = pack8bf(a0r, a1r);
        float4 blo0 = {brr[0], brr[1], brr[2], brr[3]};
        float4 bhi0 = {brr[4], brr[5], brr[6], brr[7]};
        float4 blo1 = {brr[8], brr[9], brr[10], brr[11]};
        float4 bhi1 = {brr[12], brr[13], brr[14], brr[15]};
        *(uint4*)&SMEM[4096 + bn * 32 + bk0] = pack8bf(blo0, bhi0);
        *(uint4*)&SMEM[4096 + bn * 32 + bk0 + 8] = pack8bf(blo1, bhi1);
    }
    a0r = *(const float4*)&xrow[32 + ac];
    a1r = *(const float4*)&xrow[32 + ac + 4];
#pragma unroll
    for (int j = 0; j < 16; j++) brr[j] = wcol[(size_t)(32 + bk0 + j) * EMB];

    int buf = 0;
    for (int k0 = 0; k0 < EMB; k0 += 32) {
        __syncthreads();  // buf writes visible; other buf free
        if (k0 + 32 < EMB) {
            unsigned short* A_ = &SMEM[(buf ^ 1) * 2048];
            unsigned short* B_ = &SMEM[4096 + (buf ^ 1) * 4096];
            *(uint4*)&A_[ar * 32 + ac] = pack8bf(a0r, a1r);
            float4 blo0 = {brr[0], brr[1], brr[2], brr[3]};
            float4 bhi0 = {brr[4], brr[5], brr[6], brr[7]};
            float4 blo1 = {brr[8], brr[9], brr[10], brr[11]};
            float4 bhi1 = {brr[12], brr[13], brr[14], brr[15]};
            *(uint4*)&B_[bn * 32 + bk0] = pack8bf(blo0, bhi0);
            *(uint4*)&B_[bn * 32 + bk0 + 8] = pack8bf(blo1, bhi1);
            if (k0 + 64 < EMB) {
                a0r = *(const float4*)&xrow[k0 + 64 + ac];
                a1r = *(const float4*)&xrow[k0 + 64 + ac + 4];
#pragma unroll
                for (int j = 0; j < 16; j++)
                    brr[j] = wcol[(size_t)(k0 + 64 + bk0 + j) * EMB];
            }
        }
        const unsigned short* A_ = &SMEM[buf * 2048];
        const unsigned short* B_ = &SMEM[4096 + buf * 4096];
        short8 a[2], b[4];
        for (int i = 0; i < 2; i++) a[i] = *(const short8*)&A_[(wm + i * 16 + l16) * 32 + quad * 8];
        for (int j = 0; j < 4; j++) b[j] = *(const short8*)&B_[(wn + j * 16 + l16) * 32 + quad * 8];
        for (int i = 0; i < 2; i++)
            for (int j = 0; j < 4; j++) acc[i][j] = mfma32(a[i], b[j], acc[i][j]);
        buf ^= 1;
    }

    if (z < 2) {
        const float* bias = z ? b1p : b0p;
        const float sc = z ? 1.0f : QSCALE;
        for (int i = 0; i < 2; i++)
            for (int j = 0; j < 4; j++) {
                int mbase = m0 + wm + i * 16 + quad * 4;
                int n = n0 + wn + j * 16 + l16;  // 0..1535 natural col
                float bv = bias[n - z * EMB];
                for (int r = 0; r < 4; r++)
                    QKb[(size_t)(mbase + r) * 1536 + n] = f2bf((acc[i][j][r] + bv) * sc);
            }
    } else {
        // V^T epilogue for 64-row tiles (SMEM stride 72 ush ≡ 4 mod 32: conflict-free)
        const int nn = n0 + wn + l16 - 2 * EMB;
        for (int j = 0; j < 4; j++) {
            __syncthreads();
            const float bv = b2p[nn + j * 16];
            const int nloc = (wave & 1) * 16 + l16;
            for (int i = 0; i < 2; i++) {
                ushort4 pk;
                pk.x = f2bf(acc[i][j][0] + bv);
                pk.y = f2bf(acc[i][j][1] + bv);
                pk.z = f2bf(acc[i][j][2] + bv);
                pk.w = f2bf(acc[i][j][3] + bv);
                *(ushort4*)&SMEM[nloc * 72 + wm + i * 16 + quad * 4] = pk;
            }
            __syncthreads();
            const int nl = tid >> 3, c = tid & 7;
            const int ng = (nl >> 4) * 64 + j * 16 + (nl & 15) + n0 - 2 * EMB;
            const int hh = ng >> 6, dd = ng & 63;
            unsigned short* dst = &Vtb[(size_t)(hh * HD + dd) * SEQ + m0];
            *(uint4*)&dst[c * 8] = *(uint4*)&SMEM[nl * 72 + c * 8];
        }
    }
}

// ---------------------------------------------------------------- 64x64 out-proj GEMM
__global__ __launch_bounds__(256) void gemm_out(const unsigned short* __restrict__ A,
                                                const unsigned short* __restrict__ Bt,
                                                const float* __restrict__ bias,
                                                float* __restrict__ outp) {
    __shared__ __align__(16) unsigned short SMEM[8192];  // As[2]@0/2048, Bs[2]@4096/6144
    const int tid = threadIdx.x;
    const int wave = tid >> 6, lane = tid & 63, quad = lane >> 4, l16 = lane & 15;
    const int m0 = blockIdx.x * 64, n0 = blockIdx.y * 64;
    const int wm = (wave >> 1) * 32, wn = (wave & 1) * 32;
    const int lrow = lane >> 2, lcol = (lane & 3) * 8;

    f32x4 acc[2][2] = {};

    load_lds16(&A[(size_t)(m0 + wave * 16 + lrow) * EMB + lcol], &SMEM[wave * 512]);
    load_lds16(&Bt[(size_t)(n0 + wave * 16 + lrow) * EMB + lcol], &SMEM[4096 + wave * 512]);
    int buf = 0;
    for (int k0 = 0; k0 < EMB; k0 += 32) {
        __syncthreads();
        if (k0 + 32 < EMB) {
            unsigned short* A_ = &SMEM[(buf ^ 1) * 2048];
            unsigned short* B_ = &SMEM[4096 + (buf ^ 1) * 2048];
            load_lds16(&A[(size_t)(m0 + wave * 16 + lrow) * EMB + k0 + 32 + lcol], &A_[wave * 512]);
            load_lds16(&Bt[(size_t)(n0 + wave * 16 + lrow) * EMB + k0 + 32 + lcol], &B_[wave * 512]);
        }
        const unsigned short* A_ = &SMEM[buf * 2048];
        const unsigned short* B_ = &SMEM[4096 + buf * 2048];
        short8 a[2], b[2];
        for (int i = 0; i < 2; i++) a[i] = *(const short8*)&A_[(wm + i * 16 + l16) * 32 + quad * 8];
        for (int j = 0; j < 2; j++) b[j] = *(const short8*)&B_[(wn + j * 16 + l16) * 32 + quad * 8];
        for (int i = 0; i < 2; i++)
            for (int j = 0; j < 2; j++) acc[i][j] = mfma32(a[i], b[j], acc[i][j]);
        buf ^= 1;
    }

    for (int i = 0; i < 2; i++)
        for (int j = 0; j < 2; j++) {
            int mbase = m0 + wm + i * 16 + quad * 4;
            int n = n0 + wn + j * 16 + l16;
            float bv = bias[n];
            for (int r = 0; r < 4; r++) outp[(size_t)(mbase + r) * EMB + n] = acc[i][j][r] + bv;
        }
}

// ---------------------------------------------------------------- attention
// Frozen at R20 (triple-buffered K/V, 48 KB LDS, 1 barrier/tile) — measured
// equal to R13/R16/R18/R19 at ~57 us. Attn is insensitive to every structural
// lever tried (9 variants); only software-pipelining paid (-12%, R13).
// NEVER (256,4): hipcc maps the 4th tier to a 64-VGPR cap -> spill.
__global__ __launch_bounds__(256, 3) void attn_kernel(const unsigned short* __restrict__ QKb,
                                                      const unsigned short* __restrict__ Vtb,
                                                      unsigned short* __restrict__ ctxb,
                                                      unsigned short* __restrict__ Op,
                                                      float* __restrict__ mArr,
                                                      float* __restrict__ lArr) {
    __shared__ __align__(16) unsigned short Ks3[3][64 * 64];  // 24 KB
    __shared__ __align__(16) unsigned short Vs3[3][64 * 64];  // 24 KB

    const int bid = blockIdx.x;
    const int h = bid % HEADS;
    const int r2 = 67 - bid / HEADS;  // big i128 (long chunks) first
    int i128, ch, nch;
    if (r2 < 10) {
        i128 = r2; ch = 0; nch = 1;
    } else if (r2 < 30) {
        int t = r2 - 10; i128 = 10 + (t >> 1); ch = t & 1; nch = 2;
    } else if (r2 < 60) {
        int t = r2 - 30; i128 = 20 + t / 3; ch = t % 3; nch = 3;
    } else {
        int t = r2 - 60; i128 = 30 + (t >> 2); ch = t & 3; nch = 4;
    }
    const int T = 2 * i128 + 2;
    const int kb = ch * T / nch;
    const int ke = (ch + 1) * T / nch - 1;
    const int qbase = i128 * 128;
    const int tid = threadIdx.x;
    const int wave = tid >> 6, lane = tid & 63, quad = lane >> 4, l16 = lane & 15;

    const unsigned short* Qg = QKb + (size_t)h * HD;          // row stride 1536
    const unsigned short* Kg = QKb + (size_t)(EMB + h * HD);  // row stride 1536
    const unsigned short* Vh = Vtb + (size_t)h * HD * SEQ;    // [d][m]

    const int qa = qbase + wave * 32 + l16;  // set a: waves 0..3 cover 128 q-rows
    const int qb = qa + 16;                  // set b
    const short8 bQ0a = *(const short8*)&Qg[(size_t)qa * 1536 + quad * 8];
    const short8 bQ1a = *(const short8*)&Qg[(size_t)qa * 1536 + 32 + quad * 8];
    const short8 bQ0b = *(const short8*)&Qg[(size_t)qb * 1536 + quad * 8];
    const short8 bQ1b = *(const short8*)&Qg[(size_t)qb * 1536 + 32 + quad * 8];

    const int row = tid >> 2, t4 = tid & 3;  // 256 threads: 64 rows x 4 chunks
    const int swk = row & 7, swv = row & 15;

    f32x4 Oa[4] = {}, Ob[4] = {};
    float m_a = -3.0e38f, l_a = 0.f;
    float m_b = -3.0e38f, l_b = 0.f;

    uint4 kr0, kr1, vr0, vr1;

    // ---- prologue: stage tiles kb, kb+1; keep tile kb+2 in regs
    {
        const unsigned short* kp = &Kg[(size_t)(kb * 64 + row) * 1536];
        kr0 = *(const uint4*)&kp[(2 * t4) * 8];
        kr1 = *(const uint4*)&kp[(2 * t4 + 1) * 8];
        const unsigned short* vp = &Vh[(size_t)row * SEQ + kb * 64];
        vr0 = *(const uint4*)&vp[t4 * 16];
        vr1 = *(const uint4*)&vp[t4 * 16 + 8];
        unsigned short* Kd = &Ks3[kb % 3][0];
        unsigned short* Vd = &Vs3[kb % 3][0];
        *(uint4*)&Kd[row * 64 + ((2 * t4) ^ swk) * 8] = kr0;
        *(uint4*)&Kd[row * 64 + ((2 * t4 + 1) ^ swk) * 8] = kr1;
        *(uint2*)&Vd[row * 64 + ((4 * t4) ^ swv) * 4] = ((const uint2*)&vr0)[0];
        *(uint2*)&Vd[row * 64 + ((4 * t4 + 1) ^ swv) * 4] = ((const uint2*)&vr0)[1];
        *(uint2*)&Vd[row * 64 + ((4 * t4 + 2) ^ swv) * 4] = ((const uint2*)&vr1)[0];
        *(uint2*)&Vd[row * 64 + ((4 * t4 + 3) ^ swv) * 4] = ((const uint2*)&vr1)[1];
    }
    if (kb + 1 <= ke) {
        const int nb = (kb + 1) * 64;
        const unsigned short* kp = &Kg[(size_t)(nb + row) * 1536];
        kr0 = *(const uint4*)&kp[(2 * t4) * 8];
        kr1 = *(const uint4*)&kp[(2 * t4 + 1) * 8];
        const unsigned short* vp = &Vh[(size_t)row * SEQ + nb];
        vr0 = *(const uint4*)&vp[t4 * 16];
        vr1 = *(const uint4*)&vp[t4 * 16 + 8];
        unsigned short* Kd = &Ks3[(kb + 1) % 3][0];
        unsigned short* Vd = &Vs3[(kb + 1) % 3][0];
        *(uint4*)&Kd[row * 64 + ((2 * t4) ^ swk) * 8] = kr0;
        *(uint4*)&Kd[row * 64 + ((2 * t4 + 1) ^ swk) * 8] = kr1;
        *(uint2*)&Vd[row * 64 + ((4 * t4) ^ swv) * 4] = ((const uint2*)&vr0)[0];
        *(uint2*)&Vd[row * 64 + ((4 * t4 + 1) ^ swv) * 4] = ((const uint2*)&vr0)[1];
        *(uint2*)&Vd[row * 64 + ((4 * t4 + 2) ^ swv) * 4] = ((const uint2*)&vr1)[0];
        *(uint2*)&Vd[row * 64 + ((4 * t4 + 3) ^ swv) * 4] = ((const uint2*)&vr1)[1];
    }
    if (kb + 2 <= ke) {  // tile kb+2 -> regs only
        const int nb = (kb + 2) * 64;
        const unsigned short* kp = &Kg[(size_t)(nb + row) * 1536];
        kr0 = *(const uint4*)&kp[(2 * t4) * 8];
        kr1 = *(const uint4*)&kp[(2 * t4 + 1) * 8];
        const unsigned short* vp = &Vh[(size_t)row * SEQ + nb];
        vr0 = *(const uint4*)&vp[t4 * 16];
        vr1 = *(const uint4*)&vp[t4 * 16 + 8];
    }
    __syncthreads();

    const int qw = qbase + wave * 32 + 31;  // wave's last causal q-row
    const int swr = l16 & 7;

    // prime QK(kb) -> sa/sb
    f32x4 sa[4], sb[4];
    if (kb * 64 <= qw) {
        const unsigned short* Kc = &Ks3[kb % 3][0];
        for (int nt = 0; nt < 4; nt++) {
            short8 aK0 = *(const short8*)&Kc[(nt * 16 + l16) * 64 + (quad ^ swr) * 8];
            short8 aK1 = *(const short8*)&Kc[(nt * 16 + l16) * 64 + ((quad + 4) ^ swr) * 8];
            f32x4 za = {};
            za = mfma32(aK0, bQ0a, za);
            za = mfma32(aK1, bQ1a, za);
            sa[nt] = za;
            f32x4 zb = {};
            zb = mfma32(aK0, bQ0b, zb);
            zb = mfma32(aK1, bQ1b, zb);
            sb[nt] = zb;
        }
        if (kb * 64 + 63 > qbase + wave * 32) {
            for (int nt = 0; nt < 4; nt++)
                for (int r = 0; r < 4; r++) {
                    const int kk = kb * 64 + nt * 16 + quad * 4 + r;
                    if (kk > qa) sa[nt][r] = -INFINITY;
                    if (kk > qb) sb[nt][r] = -INFINITY;
                }
        }
    }

    int b0 = kb % 3;  // buffer of tile kt
    for (int kt = kb; kt <= ke; kt++) {
        const int b1 = (b0 == 2) ? 0 : b0 + 1;  // tile kt+1
        const int b2 = (b1 == 2) ? 0 : b1 + 1;  // tile kt+2

        __syncthreads();  // stage(kt+1) visible; all waves past PV(kt-1)

        if (kt + 2 <= ke) {
            unsigned short* Kd = &Ks3[b2][0];
            unsigned short* Vd = &Vs3[b2][0];
            *(uint4*)&Kd[row * 64 + ((2 * t4) ^ swk) * 8] = kr0;
            *(uint4*)&Kd[row * 64 + ((2 * t4 + 1) ^ swk) * 8] = kr1;
            *(uint2*)&Vd[row * 64 + ((4 * t4) ^ swv) * 4] = ((const uint2*)&vr0)[0];
            *(uint2*)&Vd[row * 64 + ((4 * t4 + 1) ^ swv) * 4] = ((const uint2*)&vr0)[1];
            *(uint2*)&Vd[row * 64 + ((4 * t4 + 2) ^ swv) * 4] = ((const uint2*)&vr1)[0];
            *(uint2*)&Vd[row * 64 + ((4 * t4 + 3) ^ swv) * 4] = ((const uint2*)&vr1)[1];
            if (kt + 3 <= ke) {
                const int nb = (kt + 3) * 64;
                const unsigned short* kp = &Kg[(size_t)(nb + row) * 1536];
                kr0 = *(const uint4*)&kp[(2 * t4) * 8];
                kr1 = *(const uint4*)&kp[(2 * t4 + 1) * 8];
                const unsigned short* vp = &Vh[(size_t)row * SEQ + nb];
                vr0 = *(const uint4*)&vp[t4 * 16];
                vr1 = *(const uint4*)&vp[t4 * 16 + 8];
            }
        }

        const int kbase = kt * 64;
        const bool cur = (kbase <= qw);

        short4v pka[4], pkb[4];
        if (cur) {
            softmax_q(sa, m_a, l_a, Oa, pka);
            softmax_q(sb, m_b, l_b, Ob, pkb);
        }

        const int kn = kbase + 64;
        if (kt < ke && kn <= qw) {
            const unsigned short* Kc = &Ks3[b1][0];
            for (int nt = 0; nt < 4; nt++) {
                short8 aK0 = *(const short8*)&Kc[(nt * 16 + l16) * 64 + (quad ^ swr) * 8];
                short8 aK1 = *(const short8*)&Kc[(nt * 16 + l16) * 64 + ((quad + 4) ^ swr) * 8];
                f32x4 za = {};
                za = mfma32(aK0, bQ0a, za);
                za = mfma32(aK1, bQ1a, za);
                sa[nt] = za;
                f32x4 zb = {};
                zb = mfma32(aK0, bQ0b, zb);
                zb = mfma32(aK1, bQ1b, zb);
                sb[nt] = zb;
            }
            if (kn + 63 > qbase + wave * 32) {
                for (int nt = 0; nt < 4; nt++)
                    for (int r = 0; r < 4; r++) {
                        const int kk = kn + nt * 16 + quad * 4 + r;
                        if (kk > qa) sa[nt][r] = -INFINITY;
                        if (kk > qb) sb[nt][r] = -INFINITY;
                    }
            }
        }

        if (cur) {
            const unsigned short* Vc = &Vs3[b0][0];
            for (int dt = 0; dt < 4; dt++)
                for (int nt = 0; nt < 4; nt++) {
                    short4v av =
                        *(const short4v*)&Vc[(dt * 16 + l16) * 64 + ((4 * nt + quad) ^ l16) * 4];
                    Oa[dt] = mfma16(av, pka[nt], Oa[dt]);
                    Ob[dt] = mfma16(av, pkb[nt], Ob[dt]);
                }
        }

        b0 = b1;
    }

    // deferred cross-lane l reduction (m is quad-uniform by construction)
    l_a += __shfl_xor(l_a, 16);
    l_a += __shfl_xor(l_a, 32);
    l_b += __shfl_xor(l_b, 16);
    l_b += __shfl_xor(l_b, 32);

    const int qla = wave * 32 + l16;  // 0..127 across 4 waves (set a)
    const int qlb = qla + 16;         // set b
    if (nch == 1) {
        const float ia = 1.f / l_a, ib = 1.f / l_b;
        for (int dt = 0; dt < 4; dt++) {
            ushort4 oa, ob;
            oa.x = f2bf(Oa[dt][0] * ia);
            oa.y = f2bf(Oa[dt][1] * ia);
            oa.z = f2bf(Oa[dt][2] * ia);
            oa.w = f2bf(Oa[dt][3] * ia);
            ob.x = f2bf(Ob[dt][0] * ib);
            ob.y = f2bf(Ob[dt][1] * ib);
            ob.z = f2bf(Ob[dt][2] * ib);
            ob.w = f2bf(Ob[dt][3] * ib);
            *(ushort4*)&ctxb[(size_t)qa * EMB + h * HD + dt * 16 + quad * 4] = oa;
            *(ushort4*)&ctxb[(size_t)qb * EMB + h * HD + dt * 16 + quad * 4] = ob;
        }
    } else {
        if (ch == 0) {
            for (int dt = 0; dt < 4; dt++) {
                ushort4 oa, ob;
                oa.x = f2bf(Oa[dt][0]);
                oa.y = f2bf(Oa[dt][1]);
                oa.z = f2bf(Oa[dt][2]);
                oa.w = f2bf(Oa[dt][3]);
                ob.x = f2bf(Ob[dt][0]);
                ob.y = f2bf(Ob[dt][1]);
                ob.z = f2bf(Ob[dt][2]);
                ob.w = f2bf(Ob[dt][3]);
                *(ushort4*)&ctxb[(size_t)qa * EMB + h * HD + dt * 16 + quad * 4] = oa;
                *(ushort4*)&ctxb[(size_t)qb * EMB + h * HD + dt * 16 + quad * 4] = ob;
            }
        } else {
            const int pid = pid_of(h, i128, ch);
            for (int dt = 0; dt < 4; dt++) {
                ushort4 oa, ob;
                oa.x = f2bf(Oa[dt][0]);
                oa.y = f2bf(Oa[dt][1]);
                oa.z = f2bf(Oa[dt][2]);
                oa.w = f2bf(Oa[dt][3]);
                ob.x = f2bf(Ob[dt][0]);
                ob.y = f2bf(Ob[dt][1]);
                ob.z = f2bf(Ob[dt][2]);
                ob.w = f2bf(Ob[dt][3]);
                *(ushort4*)&Op[(size_t)pid * 8192 + qla * 64 + dt * 16 + quad * 4] = oa;
                *(ushort4*)&Op[(size_t)pid * 8192 + qlb * 64 + dt * 16 + quad * 4] = ob;
            }
        }
        if (quad == 0) {
            const int mlb = ((h * 32 + i128) * 4 + ch) * 128;
            mArr[mlb + qla] = m_a;
            lArr[mlb + qla] = l_a;
            mArr[mlb + qlb] = m_b;
            lArr[mlb + qlb] = l_b;
        }
    }
}

// ---------------------------------------------------------------- merge (i128>=10)
__global__ __launch_bounds__(256) void merge_kernel(const unsigned short* __restrict__ Op,
                                                    const float* __restrict__ mArr,
                                                    const float* __restrict__ lArr,
                                                    unsigned short* __restrict__ ctxb) {
    const int gid = blockIdx.x;  // 0..263
    const int h = gid % HEADS;
    const int i128 = 10 + gid / HEADS;
    const int nch = (i128 < 20) ? 2 : (i128 < 30) ? 3 : 4;
    const int q = threadIdx.x >> 1, d0 = (threadIdx.x & 1) * 32;
    const int mlbase = (h * 32 + i128) * 4;

    float mc[4], lc[4];
    for (int c = 0; c < nch; c++) {
        mc[c] = mArr[(mlbase + c) * 128 + q];
        lc[c] = lArr[(mlbase + c) * 128 + q];
    }
    float M = mc[0];
    for (int c = 1; c < nch; c++) M = fmaxf(M, mc[c]);
    float w[4], L = 0.f;
    for (int c = 0; c < nch; c++) {
        w[c] = __builtin_amdgcn_exp2f(mc[c] - M);
        L += w[c] * lc[c];
    }
    const float inv = 1.f / L;
    for (int c = 0; c < nch; c++) w[c] *= inv;

    unsigned short* dst = &ctxb[(size_t)(i128 * 128 + q) * EMB + h * HD + d0];
    for (int jj = 0; jj < 32; jj += 8) {
        uint4 u0 = *(const uint4*)&dst[jj];  // chunk0 (unnormalized) in place
        float f[8];
        const unsigned short* p0 = (const unsigned short*)&u0;
        for (int t = 0; t < 8; t++)
            f[t] = w[0] * __builtin_bit_cast(float, (unsigned int)p0[t] << 16);
        for (int c = 1; c < nch; c++) {
            const int pid = pid_of(h, i128, c);
            uint4 u = *(const uint4*)&Op[(size_t)pid * 8192 + q * 64 + d0 + jj];
            const unsigned short* p = (const unsigned short*)&u;
            for (int t = 0; t < 8; t++)
                f[t] += w[c] * __builtin_bit_cast(float, (unsigned int)p[t] << 16);
        }
        unsigned short o[8];
        for (int t = 0; t < 8; t++) o[t] = f2bf(f[t]);
        *(uint4*)&dst[jj] = *(uint4*)o;
    }
}

// ---------------------------------------------------------------- launch
extern "C" void kernel_launch(void* const* d_in, const int* in_sizes, int n_in,
                              void* d_out, int out_size, void* d_ws, size_t ws_size,
                              hipStream_t stream) {
    const float* x = (const float*)d_in[0];
    const float* wq = (const float*)d_in[1];
    const float* bq = (const float*)d_in[2];
    const float* wk = (const float*)d_in[3];
    const float* bk = (const float*)d_in[4];
    const float* wv = (const float*)d_in[5];
    const float* bv = (const float*)d_in[6];
    const float* wo = (const float*)d_in[7];
    const float* bo = (const float*)d_in[8];

    unsigned short* ws = (unsigned short*)d_ws;
    unsigned short* xb = ws;                          // (unused by gemm path now)
    unsigned short* wqkvT = xb + SEQ * EMB;           // (unused now)
    unsigned short* woT = wqkvT + 3 * EMB * EMB;      // 589,824
    unsigned short* QKb = woT + EMB * EMB;            // 4096*1536
    unsigned short* Vtb = QKb + (size_t)SEQ * 1536;   // 3,145,728
    unsigned short* ctxb = Vtb + HEADS * SEQ * HD;    // 3,145,728
    // attn-phase scratch aliases xb+wqkvT:
    // Op 432*8192 = 3,538,944 ush; mArr/lArr 196,608 f32 each -> ends 4,325,376
    unsigned short* Op = xb;
    float* mArr = (float*)(ws + 3538944);
    float* lArr = mArr + 196608;

    convert_wo<<<dim3(144), 256, 0, stream>>>(wo, woT);
    gemm_qkv<<<dim3(SEQ / 64, 3 * EMB / 128), 256, 0, stream>>>(
        x, wq, wk, wv, bq, bk, bv, QKb, Vtb);
    attn_kernel<<<dim3(12 * 68), 256, 0, stream>>>(QKb, Vtb, ctxb, Op, mArr, lArr);
    merge_kernel<<<dim3(264), 256, 0, stream>>>(Op, mArr, lArr, ctxb);
    gemm_out<<<dim3(SEQ / 64, EMB / 64), 256, 0, stream>>>(ctxb, woT, bo, (float*)d_out);
}

// Round 12
// 183.409 us; speedup vs baseline: 1.1943x; 1.1943x over previous
//
#include <hip/hip_runtime.h>
#include <stdint.h>

#define SEQ 4096
#define EMB 768
#define HEADS 12
#define HD 64

typedef __attribute__((ext_vector_type(8))) short short8;
typedef __attribute__((ext_vector_type(4))) short short4v;
typedef __attribute__((ext_vector_type(8))) __bf16 bf16x8;
typedef __attribute__((ext_vector_type(4))) __bf16 bf16x4;
typedef __attribute__((ext_vector_type(4))) float f32x4;

// scale * log2(e) folded into Q: (1/sqrt(64)) * 1.4426950408889634
#define QSCALE 0.18033688011112043f

static __device__ __forceinline__ unsigned short f2bf(float f) {
    unsigned int u = __builtin_bit_cast(unsigned int, f);
    unsigned int r = 0x7fffu + ((u >> 16) & 1u);
    u += r;
    return (unsigned short)(u >> 16);
}

static __device__ __forceinline__ f32x4 mfma32(short8 a, short8 b, f32x4 c) {
    return __builtin_amdgcn_mfma_f32_16x16x32_bf16(
        __builtin_bit_cast(bf16x8, a), __builtin_bit_cast(bf16x8, b), c, 0, 0, 0);
}

static __device__ __forceinline__ f32x4 mfma16(short4v a, short4v b, f32x4 c) {
#if __has_builtin(__builtin_amdgcn_mfma_f32_16x16x16_bf16)
    return __builtin_amdgcn_mfma_f32_16x16x16_bf16(
        __builtin_bit_cast(bf16x4, a), __builtin_bit_cast(bf16x4, b), c, 0, 0, 0);
#else
    return __builtin_amdgcn_mfma_f32_16x16x16bf16_1k(a, b, c, 0, 0, 0);
#endif
}

static __device__ __forceinline__ short4v pack4bf(float a, float b, float c, float d) {
#if __has_builtin(__builtin_amdgcn_cvt_pk_bf16_f32)
    typedef __attribute__((ext_vector_type(2))) __bf16 bf16x2;
    bf16x2 lo = __builtin_amdgcn_cvt_pk_bf16_f32(a, b);
    bf16x2 hi = __builtin_amdgcn_cvt_pk_bf16_f32(c, d);
    uint2 u = {__builtin_bit_cast(unsigned int, lo), __builtin_bit_cast(unsigned int, hi)};
    return __builtin_bit_cast(short4v, u);
#else
    short4v p;
    p[0] = (short)f2bf(a); p[1] = (short)f2bf(b);
    p[2] = (short)f2bf(c); p[3] = (short)f2bf(d);
    return p;
#endif
}

// two float4 -> 8 bf16 packed in a uint4
static __device__ __forceinline__ uint4 pack8bf(float4 lo, float4 hi) {
    short4v a = pack4bf(lo.x, lo.y, lo.z, lo.w);
    short4v b = pack4bf(hi.x, hi.y, hi.z, hi.w);
    uint2 ua = __builtin_bit_cast(uint2, a), ub = __builtin_bit_cast(uint2, b);
    uint4 r;
    r.x = ua.x; r.y = ua.y; r.z = ub.x; r.w = ub.y;
    return r;
}

static __device__ __forceinline__ void load_lds16(const void* g, void* l) {
    __builtin_amdgcn_global_load_lds(
        (const __attribute__((address_space(1))) unsigned int*)(uintptr_t)g,
        (__attribute__((address_space(3))) unsigned int*)(uintptr_t)l, 16, 0, 0);
}

// partial-id for (h, i128, ch>=1); 36 slots/head, 432 total
static __device__ __forceinline__ int pid_of(int h, int i128, int ch) {
    int b = (i128 < 20) ? (i128 - 10)
                        : (i128 < 30 ? 10 + (i128 - 20) * 2 : 30 + (i128 - 30) * 3);
    return h * 36 + b + (ch - 1);
}

// online-softmax step over one 64-k tile held as st[4] (S^T layout).
static __device__ __forceinline__ void softmax_q(f32x4* st, float& m_i, float& l_i,
                                                 f32x4* O, short4v* pk) {
    float t0 = fmaxf(fmaxf(st[0][0], st[0][1]), fmaxf(st[0][2], st[0][3]));
    float t1 = fmaxf(fmaxf(st[1][0], st[1][1]), fmaxf(st[1][2], st[1][3]));
    float t2 = fmaxf(fmaxf(st[2][0], st[2][1]), fmaxf(st[2][2], st[2][3]));
    float t3 = fmaxf(fmaxf(st[3][0], st[3][1]), fmaxf(st[3][2], st[3][3]));
    float mx = fmaxf(fmaxf(t0, t1), fmaxf(t2, t3));  // this lane's 16 values
    if (__ballot(mx > m_i + 5.0f)) {  // rare after warm-up
        mx = fmaxf(mx, __shfl_xor(mx, 16));
        mx = fmaxf(mx, __shfl_xor(mx, 32));  // per-q (cross-quad) max
        const bool inc = mx > m_i;
        const float mn = inc ? mx : m_i;
        const float alpha = __builtin_amdgcn_exp2f(m_i - mn);
        m_i = mn;
        l_i *= alpha;
        for (int dt = 0; dt < 4; dt++)
            for (int r = 0; r < 4; r++) O[dt][r] *= alpha;
    }
    float rs = 0.f;
    for (int nt = 0; nt < 4; nt++) {
        float p0 = __builtin_amdgcn_exp2f(st[nt][0] - m_i);
        float p1 = __builtin_amdgcn_exp2f(st[nt][1] - m_i);
        float p2 = __builtin_amdgcn_exp2f(st[nt][2] - m_i);
        float p3 = __builtin_amdgcn_exp2f(st[nt][3] - m_i);
        rs += p0 + p1 + p2 + p3;
        pk[nt] = pack4bf(p0, p1, p2, p3);
    }
    l_i += rs;  // per-lane partial; reduced across quads at epilogue
}

// ---------------------------------------------------------------- weight convert
// R22: weights only (576 blocks). The x conversion is fused into gemm_qkv's
// A-staging (fp32 read -> cvt_pk -> ds_write, conflict-free), deleting the
// xb round-trip (~37 MB). The B/W transpose stays HERE: R21 proved on-the-fly
// W-transpose staging costs 4.5M LDS bank conflicts + 16 gathers/thread
// (gemm_qkv 41 -> 79 us). bf16 wqkvT + DMA staging is the measured optimum.
__global__ __launch_bounds__(256) void convert_w(const float* __restrict__ wq,
                                                 const float* __restrict__ wk,
                                                 const float* __restrict__ wv,
                                                 const float* __restrict__ wo,
                                                 unsigned short* __restrict__ wqkvT,
                                                 unsigned short* __restrict__ woT) {
    __shared__ float Ls[64][65];
    const int idx = blockIdx.x;  // 0..575
    const int z = idx / 144;
    const int bx = (idx % 144) / 12, by = idx % 12;
    const float* W = (z == 0) ? wq : (z == 1) ? wk : (z == 2) ? wv : wo;
    unsigned short* dst = (z < 3) ? (wqkvT + (size_t)z * EMB * EMB) : woT;
    const int k0 = bx * 64, n0 = by * 64;
    const int r = threadIdx.x >> 2, c0 = (threadIdx.x & 3) * 16;
    for (int j = 0; j < 16; j += 4) {
        float4 v = *(const float4*)&W[(size_t)(k0 + r) * EMB + n0 + c0 + j];
        Ls[r][c0 + j] = v.x;
        Ls[r][c0 + j + 1] = v.y;
        Ls[r][c0 + j + 2] = v.z;
        Ls[r][c0 + j + 3] = v.w;
    }
    __syncthreads();
    unsigned short tmp[16];
    for (int j = 0; j < 16; j++) tmp[j] = f2bf(Ls[c0 + j][r]);
    *(uint4*)&dst[(size_t)(n0 + r) * EMB + k0 + c0] = *(uint4*)tmp;
    *(uint4*)&dst[(size_t)(n0 + r) * EMB + k0 + c0 + 8] = *(uint4*)(tmp + 8);
}

// ---------------------------------------------------------------- 64x128 QKV GEMM
// R22: A staged DIRECTLY from fp32 x (2 float4 loads -> cvt_pk -> 1 b128
// ds_write; bank-check: lane banks (ar*16+(tid&3)*4)%32 tile all 32 banks at
// the 8-deep minimum -> conflict-free). B staged from bf16 wqkvT via DMA
// (R19-proven, 0 conflicts). Double-buffered, reg-prefetch for A, 1 barrier
// per K-step.
__global__ __launch_bounds__(256) void gemm_qkv(const float* __restrict__ x,
                                                const unsigned short* __restrict__ Bt,
                                                const float* __restrict__ b0p,
                                                const float* __restrict__ b1p,
                                                const float* __restrict__ b2p,
                                                unsigned short* __restrict__ QKb,
                                                unsigned short* __restrict__ Vtb) {
    __shared__ __align__(16) unsigned short SMEM[12288];  // As[2]@0/2048 (64x32), Bs[2]@4096/8192 (128x32)
    const int tid = threadIdx.x;
    const int wave = tid >> 6, lane = tid & 63, quad = lane >> 4, l16 = lane & 15;
    const int m0 = blockIdx.x * 64, n0 = blockIdx.y * 128;
    const int wm = (wave >> 1) * 32, wn = (wave & 1) * 64;
    const int lrow = lane >> 2, lcol = (lane & 3) * 8;

    // A staging mapping: 64 rows x 4 chunks of 8 cols
    const int ar = tid >> 2, ac = (tid & 3) * 8;
    const float* xrow = x + (size_t)(m0 + ar) * EMB;

    f32x4 acc[2][4] = {};
    float4 a0r, a1r;

    // ---- prologue: A(k0=0) regs -> buf0; B(k0=0) DMA -> buf0; A(k0=32) -> regs
    a0r = *(const float4*)&xrow[ac];
    a1r = *(const float4*)&xrow[ac + 4];
    *(uint4*)&SMEM[ar * 32 + ac] = pack8bf(a0r, a1r);
    for (int t = 0; t < 2; t++) {
        int row = wave * 32 + t * 16 + lrow;
        load_lds16(&Bt[(size_t)(n0 + row) * EMB + lcol], &SMEM[4096 + (wave * 2 + t) * 512]);
    }
    a0r = *(const float4*)&xrow[32 + ac];
    a1r = *(const float4*)&xrow[32 + ac + 4];

    int buf = 0;
    for (int k0 = 0; k0 < EMB; k0 += 32) {
        __syncthreads();  // buf ready (DMA drained, A writes visible); other buf free
        if (k0 + 32 < EMB) {
            unsigned short* A_ = &SMEM[(buf ^ 1) * 2048];
            unsigned short* B_ = &SMEM[4096 + (buf ^ 1) * 4096];
            *(uint4*)&A_[ar * 32 + ac] = pack8bf(a0r, a1r);
            for (int t = 0; t < 2; t++) {
                int row = wave * 32 + t * 16 + lrow;
                load_lds16(&Bt[(size_t)(n0 + row) * EMB + k0 + 32 + lcol], &B_[(wave * 2 + t) * 512]);
            }
            if (k0 + 64 < EMB) {
                a0r = *(const float4*)&xrow[k0 + 64 + ac];
                a1r = *(const float4*)&xrow[k0 + 64 + ac + 4];
            }
        }
        const unsigned short* A_ = &SMEM[buf * 2048];
        const unsigned short* B_ = &SMEM[4096 + buf * 4096];
        short8 a[2], b[4];
        for (int i = 0; i < 2; i++) a[i] = *(const short8*)&A_[(wm + i * 16 + l16) * 32 + quad * 8];
        for (int j = 0; j < 4; j++) b[j] = *(const short8*)&B_[(wn + j * 16 + l16) * 32 + quad * 8];
        for (int i = 0; i < 2; i++)
            for (int j = 0; j < 4; j++) acc[i][j] = mfma32(a[i], b[j], acc[i][j]);
        buf ^= 1;
    }

    const int z = n0 / EMB;  // block-uniform: 0=Q, 1=K, 2=V
    if (z < 2) {
        const float* bias = z ? b1p : b0p;
        const float sc = z ? 1.0f : QSCALE;
        for (int i = 0; i < 2; i++)
            for (int j = 0; j < 4; j++) {
                int mbase = m0 + wm + i * 16 + quad * 4;
                int n = n0 + wn + j * 16 + l16;  // 0..1535 natural col
                float bv = bias[n - z * EMB];
                for (int r = 0; r < 4; r++)
                    QKb[(size_t)(mbase + r) * 1536 + n] = f2bf((acc[i][j][r] + bv) * sc);
            }
    } else {
        // V^T epilogue for 64-row tiles (SMEM stride 72 ush ≡ 4 mod 32: conflict-free)
        const int nn = n0 + wn + l16 - 2 * EMB;
        for (int j = 0; j < 4; j++) {
            __syncthreads();
            const float bv = b2p[nn + j * 16];
            const int nloc = (wave & 1) * 16 + l16;
            for (int i = 0; i < 2; i++) {
                ushort4 pk;
                pk.x = f2bf(acc[i][j][0] + bv);
                pk.y = f2bf(acc[i][j][1] + bv);
                pk.z = f2bf(acc[i][j][2] + bv);
                pk.w = f2bf(acc[i][j][3] + bv);
                *(ushort4*)&SMEM[nloc * 72 + wm + i * 16 + quad * 4] = pk;
            }
            __syncthreads();
            const int nl = tid >> 3, c = tid & 7;
            const int ng = (nl >> 4) * 64 + j * 16 + (nl & 15) + n0 - 2 * EMB;
            const int hh = ng >> 6, dd = ng & 63;
            unsigned short* dst = &Vtb[(size_t)(hh * HD + dd) * SEQ + m0];
            *(uint4*)&dst[c * 8] = *(uint4*)&SMEM[nl * 72 + c * 8];
        }
    }
}

// ---------------------------------------------------------------- 64x64 out-proj GEMM
__global__ __launch_bounds__(256) void gemm_out(const unsigned short* __restrict__ A,
                                                const unsigned short* __restrict__ Bt,
                                                const float* __restrict__ bias,
                                                float* __restrict__ outp) {
    __shared__ __align__(16) unsigned short SMEM[8192];  // As[2]@0/2048, Bs[2]@4096/6144
    const int tid = threadIdx.x;
    const int wave = tid >> 6, lane = tid & 63, quad = lane >> 4, l16 = lane & 15;
    const int m0 = blockIdx.x * 64, n0 = blockIdx.y * 64;
    const int wm = (wave >> 1) * 32, wn = (wave & 1) * 32;
    const int lrow = lane >> 2, lcol = (lane & 3) * 8;

    f32x4 acc[2][2] = {};

    load_lds16(&A[(size_t)(m0 + wave * 16 + lrow) * EMB + lcol], &SMEM[wave * 512]);
    load_lds16(&Bt[(size_t)(n0 + wave * 16 + lrow) * EMB + lcol], &SMEM[4096 + wave * 512]);
    int buf = 0;
    for (int k0 = 0; k0 < EMB; k0 += 32) {
        __syncthreads();
        if (k0 + 32 < EMB) {
            unsigned short* A_ = &SMEM[(buf ^ 1) * 2048];
            unsigned short* B_ = &SMEM[4096 + (buf ^ 1) * 2048];
            load_lds16(&A[(size_t)(m0 + wave * 16 + lrow) * EMB + k0 + 32 + lcol], &A_[wave * 512]);
            load_lds16(&Bt[(size_t)(n0 + wave * 16 + lrow) * EMB + k0 + 32 + lcol], &B_[wave * 512]);
        }
        const unsigned short* A_ = &SMEM[buf * 2048];
        const unsigned short* B_ = &SMEM[4096 + buf * 2048];
        short8 a[2], b[2];
        for (int i = 0; i < 2; i++) a[i] = *(const short8*)&A_[(wm + i * 16 + l16) * 32 + quad * 8];
        for (int j = 0; j < 2; j++) b[j] = *(const short8*)&B_[(wn + j * 16 + l16) * 32 + quad * 8];
        for (int i = 0; i < 2; i++)
            for (int j = 0; j < 2; j++) acc[i][j] = mfma32(a[i], b[j], acc[i][j]);
        buf ^= 1;
    }

    for (int i = 0; i < 2; i++)
        for (int j = 0; j < 2; j++) {
            int mbase = m0 + wm + i * 16 + quad * 4;
            int n = n0 + wn + j * 16 + l16;
            float bv = bias[n];
            for (int r = 0; r < 4; r++) outp[(size_t)(mbase + r) * EMB + n] = acc[i][j][r] + bv;
        }
}

// ---------------------------------------------------------------- attention
// Frozen at R20 (triple-buffered K/V, 48 KB LDS, 1 barrier/tile) — measured
// ~57 us, equal to R13/R16/R18/R19; insensitive to 9 structural variants.
// NEVER (256,4): hipcc maps the 4th tier to a 64-VGPR cap -> spill.
__global__ __launch_bounds__(256, 3) void attn_kernel(const unsigned short* __restrict__ QKb,
                                                      const unsigned short* __restrict__ Vtb,
                                                      unsigned short* __restrict__ ctxb,
                                                      unsigned short* __restrict__ Op,
                                                      float* __restrict__ mArr,
                                                      float* __restrict__ lArr) {
    __shared__ __align__(16) unsigned short Ks3[3][64 * 64];  // 24 KB
    __shared__ __align__(16) unsigned short Vs3[3][64 * 64];  // 24 KB

    const int bid = blockIdx.x;
    const int h = bid % HEADS;
    const int r2 = 67 - bid / HEADS;  // big i128 (long chunks) first
    int i128, ch, nch;
    if (r2 < 10) {
        i128 = r2; ch = 0; nch = 1;
    } else if (r2 < 30) {
        int t = r2 - 10; i128 = 10 + (t >> 1); ch = t & 1; nch = 2;
    } else if (r2 < 60) {
        int t = r2 - 30; i128 = 20 + t / 3; ch = t % 3; nch = 3;
    } else {
        int t = r2 - 60; i128 = 30 + (t >> 2); ch = t & 3; nch = 4;
    }
    const int T = 2 * i128 + 2;
    const int kb = ch * T / nch;
    const int ke = (ch + 1) * T / nch - 1;
    const int qbase = i128 * 128;
    const int tid = threadIdx.x;
    const int wave = tid >> 6, lane = tid & 63, quad = lane >> 4, l16 = lane & 15;

    const unsigned short* Qg = QKb + (size_t)h * HD;          // row stride 1536
    const unsigned short* Kg = QKb + (size_t)(EMB + h * HD);  // row stride 1536
    const unsigned short* Vh = Vtb + (size_t)h * HD * SEQ;    // [d][m]

    const int qa = qbase + wave * 32 + l16;  // set a: waves 0..3 cover 128 q-rows
    const int qb = qa + 16;                  // set b
    const short8 bQ0a = *(const short8*)&Qg[(size_t)qa * 1536 + quad * 8];
    const short8 bQ1a = *(const short8*)&Qg[(size_t)qa * 1536 + 32 + quad * 8];
    const short8 bQ0b = *(const short8*)&Qg[(size_t)qb * 1536 + quad * 8];
    const short8 bQ1b = *(const short8*)&Qg[(size_t)qb * 1536 + 32 + quad * 8];

    const int row = tid >> 2, t4 = tid & 3;  // 256 threads: 64 rows x 4 chunks
    const int swk = row & 7, swv = row & 15;

    f32x4 Oa[4] = {}, Ob[4] = {};
    float m_a = -3.0e38f, l_a = 0.f;
    float m_b = -3.0e38f, l_b = 0.f;

    uint4 kr0, kr1, vr0, vr1;

    // ---- prologue: stage tiles kb, kb+1; keep tile kb+2 in regs
    {
        const unsigned short* kp = &Kg[(size_t)(kb * 64 + row) * 1536];
        kr0 = *(const uint4*)&kp[(2 * t4) * 8];
        kr1 = *(const uint4*)&kp[(2 * t4 + 1) * 8];
        const unsigned short* vp = &Vh[(size_t)row * SEQ + kb * 64];
        vr0 = *(const uint4*)&vp[t4 * 16];
        vr1 = *(const uint4*)&vp[t4 * 16 + 8];
        unsigned short* Kd = &Ks3[kb % 3][0];
        unsigned short* Vd = &Vs3[kb % 3][0];
        *(uint4*)&Kd[row * 64 + ((2 * t4) ^ swk) * 8] = kr0;
        *(uint4*)&Kd[row * 64 + ((2 * t4 + 1) ^ swk) * 8] = kr1;
        *(uint2*)&Vd[row * 64 + ((4 * t4) ^ swv) * 4] = ((const uint2*)&vr0)[0];
        *(uint2*)&Vd[row * 64 + ((4 * t4 + 1) ^ swv) * 4] = ((const uint2*)&vr0)[1];
        *(uint2*)&Vd[row * 64 + ((4 * t4 + 2) ^ swv) * 4] = ((const uint2*)&vr1)[0];
        *(uint2*)&Vd[row * 64 + ((4 * t4 + 3) ^ swv) * 4] = ((const uint2*)&vr1)[1];
    }
    if (kb + 1 <= ke) {
        const int nb = (kb + 1) * 64;
        const unsigned short* kp = &Kg[(size_t)(nb + row) * 1536];
        kr0 = *(const uint4*)&kp[(2 * t4) * 8];
        kr1 = *(const uint4*)&kp[(2 * t4 + 1) * 8];
        const unsigned short* vp = &Vh[(size_t)row * SEQ + nb];
        vr0 = *(const uint4*)&vp[t4 * 16];
        vr1 = *(const uint4*)&vp[t4 * 16 + 8];
        unsigned short* Kd = &Ks3[(kb + 1) % 3][0];
        unsigned short* Vd = &Vs3[(kb + 1) % 3][0];
        *(uint4*)&Kd[row * 64 + ((2 * t4) ^ swk) * 8] = kr0;
        *(uint4*)&Kd[row * 64 + ((2 * t4 + 1) ^ swk) * 8] = kr1;
        *(uint2*)&Vd[row * 64 + ((4 * t4) ^ swv) * 4] = ((const uint2*)&vr0)[0];
        *(uint2*)&Vd[row * 64 + ((4 * t4 + 1) ^ swv) * 4] = ((const uint2*)&vr0)[1];
        *(uint2*)&Vd[row * 64 + ((4 * t4 + 2) ^ swv) * 4] = ((const uint2*)&vr1)[0];
        *(uint2*)&Vd[row * 64 + ((4 * t4 + 3) ^ swv) * 4] = ((const uint2*)&vr1)[1];
    }
    if (kb + 2 <= ke) {  // tile kb+2 -> regs only
        const int nb = (kb + 2) * 64;
        const unsigned short* kp = &Kg[(size_t)(nb + row) * 1536];
        kr0 = *(const uint4*)&kp[(2 * t4) * 8];
        kr1 = *(const uint4*)&kp[(2 * t4 + 1) * 8];
        const unsigned short* vp = &Vh[(size_t)row * SEQ + nb];
        vr0 = *(const uint4*)&vp[t4 * 16];
        vr1 = *(const uint4*)&vp[t4 * 16 + 8];
    }
    __syncthreads();

    const int qw = qbase + wave * 32 + 31;  // wave's last causal q-row
    const int swr = l16 & 7;

    // prime QK(kb) -> sa/sb
    f32x4 sa[4], sb[4];
    if (kb * 64 <= qw) {
        const unsigned short* Kc = &Ks3[kb % 3][0];
        for (int nt = 0; nt < 4; nt++) {
            short8 aK0 = *(const short8*)&Kc[(nt * 16 + l16) * 64 + (quad ^ swr) * 8];
            short8 aK1 = *(const short8*)&Kc[(nt * 16 + l16) * 64 + ((quad + 4) ^ swr) * 8];
            f32x4 za = {};
            za = mfma32(aK0, bQ0a, za);
            za = mfma32(aK1, bQ1a, za);
            sa[nt] = za;
            f32x4 zb = {};
            zb = mfma32(aK0, bQ0b, zb);
            zb = mfma32(aK1, bQ1b, zb);
            sb[nt] = zb;
        }
        if (kb * 64 + 63 > qbase + wave * 32) {
            for (int nt = 0; nt < 4; nt++)
                for (int r = 0; r < 4; r++) {
                    const int kk = kb * 64 + nt * 16 + quad * 4 + r;
                    if (kk > qa) sa[nt][r] = -INFINITY;
                    if (kk > qb) sb[nt][r] = -INFINITY;
                }
        }
    }

    int b0 = kb % 3;  // buffer of tile kt
    for (int kt = kb; kt <= ke; kt++) {
        const int b1 = (b0 == 2) ? 0 : b0 + 1;  // tile kt+1
        const int b2 = (b1 == 2) ? 0 : b1 + 1;  // tile kt+2

        __syncthreads();  // stage(kt+1) visible; all waves past PV(kt-1)

        if (kt + 2 <= ke) {
            unsigned short* Kd = &Ks3[b2][0];
            unsigned short* Vd = &Vs3[b2][0];
            *(uint4*)&Kd[row * 64 + ((2 * t4) ^ swk) * 8] = kr0;
            *(uint4*)&Kd[row * 64 + ((2 * t4 + 1) ^ swk) * 8] = kr1;
            *(uint2*)&Vd[row * 64 + ((4 * t4) ^ swv) * 4] = ((const uint2*)&vr0)[0];
            *(uint2*)&Vd[row * 64 + ((4 * t4 + 1) ^ swv) * 4] = ((const uint2*)&vr0)[1];
            *(uint2*)&Vd[row * 64 + ((4 * t4 + 2) ^ swv) * 4] = ((const uint2*)&vr1)[0];
            *(uint2*)&Vd[row * 64 + ((4 * t4 + 3) ^ swv) * 4] = ((const uint2*)&vr1)[1];
            if (kt + 3 <= ke) {
                const int nb = (kt + 3) * 64;
                const unsigned short* kp = &Kg[(size_t)(nb + row) * 1536];
                kr0 = *(const uint4*)&kp[(2 * t4) * 8];
                kr1 = *(const uint4*)&kp[(2 * t4 + 1) * 8];
                const unsigned short* vp = &Vh[(size_t)row * SEQ + nb];
                vr0 = *(const uint4*)&vp[t4 * 16];
                vr1 = *(const uint4*)&vp[t4 * 16 + 8];
            }
        }

        const int kbase = kt * 64;
        const bool cur = (kbase <= qw);

        short4v pka[4], pkb[4];
        if (cur) {
            softmax_q(sa, m_a, l_a, Oa, pka);
            softmax_q(sb, m_b, l_b, Ob, pkb);
        }

        const int kn = kbase + 64;
        if (kt < ke && kn <= qw) {
            const unsigned short* Kc = &Ks3[b1][0];
            for (int nt = 0; nt < 4; nt++) {
                short8 aK0 = *(const short8*)&Kc[(nt * 16 + l16) * 64 + (quad ^ swr) * 8];
                short8 aK1 = *(const short8*)&Kc[(nt * 16 + l16) * 64 + ((quad + 4) ^ swr) * 8];
                f32x4 za = {};
                za = mfma32(aK0, bQ0a, za);
                za = mfma32(aK1, bQ1a, za);
                sa[nt] = za;
                f32x4 zb = {};
                zb = mfma32(aK0, bQ0b, zb);
                zb = mfma32(aK1, bQ1b, zb);
                sb[nt] = zb;
            }
            if (kn + 63 > qbase + wave * 32) {
                for (int nt = 0; nt < 4; nt++)
                    for (int r = 0; r < 4; r++) {
                        const int kk = kn + nt * 16 + quad * 4 + r;
                        if (kk > qa) sa[nt][r] = -INFINITY;
                        if (kk > qb) sb[nt][r] = -INFINITY;
                    }
            }
        }

        if (cur) {
            const unsigned short* Vc = &Vs3[b0][0];
            for (int dt = 0; dt < 4; dt++)
                for (int nt = 0; nt < 4; nt++) {
                    short4v av =
                        *(const short4v*)&Vc[(dt * 16 + l16) * 64 + ((4 * nt + quad) ^ l16) * 4];
                    Oa[dt] = mfma16(av, pka[nt], Oa[dt]);
                    Ob[dt] = mfma16(av, pkb[nt], Ob[dt]);
                }
        }

        b0 = b1;
    }

    // deferred cross-lane l reduction (m is quad-uniform by construction)
    l_a += __shfl_xor(l_a, 16);
    l_a += __shfl_xor(l_a, 32);
    l_b += __shfl_xor(l_b, 16);
    l_b += __shfl_xor(l_b, 32);

    const int qla = wave * 32 + l16;  // 0..127 across 4 waves (set a)
    const int qlb = qla + 16;         // set b
    if (nch == 1) {
        const float ia = 1.f / l_a, ib = 1.f / l_b;
        for (int dt = 0; dt < 4; dt++) {
            ushort4 oa, ob;
            oa.x = f2bf(Oa[dt][0] * ia);
            oa.y = f2bf(Oa[dt][1] * ia);
            oa.z = f2bf(Oa[dt][2] * ia);
            oa.w = f2bf(Oa[dt][3] * ia);
            ob.x = f2bf(Ob[dt][0] * ib);
            ob.y = f2bf(Ob[dt][1] * ib);
            ob.z = f2bf(Ob[dt][2] * ib);
            ob.w = f2bf(Ob[dt][3] * ib);
            *(ushort4*)&ctxb[(size_t)qa * EMB + h * HD + dt * 16 + quad * 4] = oa;
            *(ushort4*)&ctxb[(size_t)qb * EMB + h * HD + dt * 16 + quad * 4] = ob;
        }
    } else {
        if (ch == 0) {
            for (int dt = 0; dt < 4; dt++) {
                ushort4 oa, ob;
                oa.x = f2bf(Oa[dt][0]);
                oa.y = f2bf(Oa[dt][1]);
                oa.z = f2bf(Oa[dt][2]);
                oa.w = f2bf(Oa[dt][3]);
                ob.x = f2bf(Ob[dt][0]);
                ob.y = f2bf(Ob[dt][1]);
                ob.z = f2bf(Ob[dt][2]);
                ob.w = f2bf(Ob[dt][3]);
                *(ushort4*)&ctxb[(size_t)qa * EMB + h * HD + dt * 16 + quad * 4] = oa;
                *(ushort4*)&ctxb[(size_t)qb * EMB + h * HD + dt * 16 + quad * 4] = ob;
            }
        } else {
            const int pid = pid_of(h, i128, ch);
            for (int dt = 0; dt < 4; dt++) {
                ushort4 oa, ob;
                oa.x = f2bf(Oa[dt][0]);
                oa.y = f2bf(Oa[dt][1]);
                oa.z = f2bf(Oa[dt][2]);
                oa.w = f2bf(Oa[dt][3]);
                ob.x = f2bf(Ob[dt][0]);
                ob.y = f2bf(Ob[dt][1]);
                ob.z = f2bf(Ob[dt][2]);
                ob.w = f2bf(Ob[dt][3]);
                *(ushort4*)&Op[(size_t)pid * 8192 + qla * 64 + dt * 16 + quad * 4] = oa;
                *(ushort4*)&Op[(size_t)pid * 8192 + qlb * 64 + dt * 16 + quad * 4] = ob;
            }
        }
        if (quad == 0) {
            const int mlb = ((h * 32 + i128) * 4 + ch) * 128;
            mArr[mlb + qla] = m_a;
            lArr[mlb + qla] = l_a;
            mArr[mlb + qlb] = m_b;
            lArr[mlb + qlb] = l_b;
        }
    }
}

// ---------------------------------------------------------------- merge (i128>=10)
__global__ __launch_bounds__(256) void merge_kernel(const unsigned short* __restrict__ Op,
                                                    const float* __restrict__ mArr,
                                                    const float* __restrict__ lArr,
                                                    unsigned short* __restrict__ ctxb) {
    const int gid = blockIdx.x;  // 0..263
    const int h = gid % HEADS;
    const int i128 = 10 + gid / HEADS;
    const int nch = (i128 < 20) ? 2 : (i128 < 30) ? 3 : 4;
    const int q = threadIdx.x >> 1, d0 = (threadIdx.x & 1) * 32;
    const int mlbase = (h * 32 + i128) * 4;

    float mc[4], lc[4];
    for (int c = 0; c < nch; c++) {
        mc[c] = mArr[(mlbase + c) * 128 + q];
        lc[c] = lArr[(mlbase + c) * 128 + q];
    }
    float M = mc[0];
    for (int c = 1; c < nch; c++) M = fmaxf(M, mc[c]);
    float w[4], L = 0.f;
    for (int c = 0; c < nch; c++) {
        w[c] = __builtin_amdgcn_exp2f(mc[c] - M);
        L += w[c] * lc[c];
    }
    const float inv = 1.f / L;
    for (int c = 0; c < nch; c++) w[c] *= inv;

    unsigned short* dst = &ctxb[(size_t)(i128 * 128 + q) * EMB + h * HD + d0];
    for (int jj = 0; jj < 32; jj += 8) {
        uint4 u0 = *(const uint4*)&dst[jj];  // chunk0 (unnormalized) in place
        float f[8];
        const unsigned short* p0 = (const unsigned short*)&u0;
        for (int t = 0; t < 8; t++)
            f[t] = w[0] * __builtin_bit_cast(float, (unsigned int)p0[t] << 16);
        for (int c = 1; c < nch; c++) {
            const int pid = pid_of(h, i128, c);
            uint4 u = *(const uint4*)&Op[(size_t)pid * 8192 + q * 64 + d0 + jj];
            const unsigned short* p = (const unsigned short*)&u;
            for (int t = 0; t < 8; t++)
                f[t] += w[c] * __builtin_bit_cast(float, (unsigned int)p[t] << 16);
        }
        unsigned short o[8];
        for (int t = 0; t < 8; t++) o[t] = f2bf(f[t]);
        *(uint4*)&dst[jj] = *(uint4*)o;
    }
}

// ---------------------------------------------------------------- launch
extern "C" void kernel_launch(void* const* d_in, const int* in_sizes, int n_in,
                              void* d_out, int out_size, void* d_ws, size_t ws_size,
                              hipStream_t stream) {
    const float* x = (const float*)d_in[0];
    const float* wq = (const float*)d_in[1];
    const float* bq = (const float*)d_in[2];
    const float* wk = (const float*)d_in[3];
    const float* bk = (const float*)d_in[4];
    const float* wv = (const float*)d_in[5];
    const float* bv = (const float*)d_in[6];
    const float* wo = (const float*)d_in[7];
    const float* bo = (const float*)d_in[8];

    unsigned short* ws = (unsigned short*)d_ws;
    unsigned short* xb = ws;                          // free region (x no longer staged)
    unsigned short* wqkvT = xb + SEQ * EMB;           // 1,769,472
    unsigned short* woT = wqkvT + 3 * EMB * EMB;      // 589,824
    unsigned short* QKb = woT + EMB * EMB;            // 4096*1536
    unsigned short* Vtb = QKb + (size_t)SEQ * 1536;   // 3,145,728
    unsigned short* ctxb = Vtb + HEADS * SEQ * HD;    // 3,145,728
    // attn-phase scratch aliases xb+wqkvT (dead after gemm_qkv):
    // Op 432*8192 = 3,538,944 ush; mArr/lArr 196,608 f32 each -> ends 4,325,376
    unsigned short* Op = xb;
    float* mArr = (float*)(ws + 3538944);
    float* lArr = mArr + 196608;

    convert_w<<<dim3(576), 256, 0, stream>>>(wq, wk, wv, wo, wqkvT, woT);
    gemm_qkv<<<dim3(SEQ / 64, 3 * EMB / 128), 256, 0, stream>>>(
        x, wqkvT, bq, bk, bv, QKb, Vtb);
    attn_kernel<<<dim3(12 * 68), 256, 0, stream>>>(QKb, Vtb, ctxb, Op, mArr, lArr);
    merge_kernel<<<dim3(264), 256, 0, stream>>>(Op, mArr, lArr, ctxb);
    gemm_out<<<dim3(SEQ / 64, EMB / 64), 256, 0, stream>>>(ctxb, woT, bo, (float*)d_out);
}

// Round 14
// 180.873 us; speedup vs baseline: 1.2110x; 1.0140x over previous
//
#include <hip/hip_runtime.h>
#include <stdint.h>

#define SEQ 4096
#define EMB 768
#define HEADS 12
#define HD 64

typedef __attribute__((ext_vector_type(8))) short short8;
typedef __attribute__((ext_vector_type(4))) short short4v;
typedef __attribute__((ext_vector_type(8))) __bf16 bf16x8;
typedef __attribute__((ext_vector_type(4))) __bf16 bf16x4;
typedef __attribute__((ext_vector_type(4))) float f32x4;

// scale * log2(e) folded into Q: (1/sqrt(64)) * 1.4426950408889634
#define QSCALE 0.18033688011112043f

static __device__ __forceinline__ unsigned short f2bf(float f) {
    unsigned int u = __builtin_bit_cast(unsigned int, f);
    unsigned int r = 0x7fffu + ((u >> 16) & 1u);
    u += r;
    return (unsigned short)(u >> 16);
}

static __device__ __forceinline__ f32x4 mfma32(short8 a, short8 b, f32x4 c) {
    return __builtin_amdgcn_mfma_f32_16x16x32_bf16(
        __builtin_bit_cast(bf16x8, a), __builtin_bit_cast(bf16x8, b), c, 0, 0, 0);
}

static __device__ __forceinline__ f32x4 mfma16(short4v a, short4v b, f32x4 c) {
#if __has_builtin(__builtin_amdgcn_mfma_f32_16x16x16_bf16)
    return __builtin_amdgcn_mfma_f32_16x16x16_bf16(
        __builtin_bit_cast(bf16x4, a), __builtin_bit_cast(bf16x4, b), c, 0, 0, 0);
#else
    return __builtin_amdgcn_mfma_f32_16x16x16bf16_1k(a, b, c, 0, 0, 0);
#endif
}

static __device__ __forceinline__ short4v pack4bf(float a, float b, float c, float d) {
#if __has_builtin(__builtin_amdgcn_cvt_pk_bf16_f32)
    typedef __attribute__((ext_vector_type(2))) __bf16 bf16x2;
    bf16x2 lo = __builtin_amdgcn_cvt_pk_bf16_f32(a, b);
    bf16x2 hi = __builtin_amdgcn_cvt_pk_bf16_f32(c, d);
    uint2 u = {__builtin_bit_cast(unsigned int, lo), __builtin_bit_cast(unsigned int, hi)};
    return __builtin_bit_cast(short4v, u);
#else
    short4v p;
    p[0] = (short)f2bf(a); p[1] = (short)f2bf(b);
    p[2] = (short)f2bf(c); p[3] = (short)f2bf(d);
    return p;
#endif
}

static __device__ __forceinline__ void load_lds16(const void* g, void* l) {
    __builtin_amdgcn_global_load_lds(
        (const __attribute__((address_space(1))) unsigned int*)(uintptr_t)g,
        (__attribute__((address_space(3))) unsigned int*)(uintptr_t)l, 16, 0, 0);
}

// partial-id for (h, i128, ch>=1); 36 slots/head, 432 total
static __device__ __forceinline__ int pid_of(int h, int i128, int ch) {
    int b = (i128 < 20) ? (i128 - 10)
                        : (i128 < 30 ? 10 + (i128 - 20) * 2 : 30 + (i128 - 30) * 3);
    return h * 36 + b + (ch - 1);
}

// online-softmax step over one 64-k tile held as st[4] (S^T layout).
// Common path is LANE-LOCAL only (15-op fmax tree). Cross-quad reduce +
// rescale live inside the rare defer-max branch. m_i stays quad-uniform by
// induction, so P fed to the k-spanning PV MFMA is consistently normalized.
static __device__ __forceinline__ void softmax_q(f32x4* st, float& m_i, float& l_i,
                                                 f32x4* O, short4v* pk) {
    float t0 = fmaxf(fmaxf(st[0][0], st[0][1]), fmaxf(st[0][2], st[0][3]));
    float t1 = fmaxf(fmaxf(st[1][0], st[1][1]), fmaxf(st[1][2], st[1][3]));
    float t2 = fmaxf(fmaxf(st[2][0], st[2][1]), fmaxf(st[2][2], st[2][3]));
    float t3 = fmaxf(fmaxf(st[3][0], st[3][1]), fmaxf(st[3][2], st[3][3]));
    float mx = fmaxf(fmaxf(t0, t1), fmaxf(t2, t3));  // this lane's 16 values
    if (__ballot(mx > m_i + 5.0f)) {  // rare after warm-up
        mx = fmaxf(mx, __shfl_xor(mx, 16));
        mx = fmaxf(mx, __shfl_xor(mx, 32));  // per-q (cross-quad) max
        const bool inc = mx > m_i;
        const float mn = inc ? mx : m_i;
        const float alpha = __builtin_amdgcn_exp2f(m_i - mn);
        m_i = mn;
        l_i *= alpha;
        for (int dt = 0; dt < 4; dt++)
            for (int r = 0; r < 4; r++) O[dt][r] *= alpha;
    }
    float rs = 0.f;
    for (int nt = 0; nt < 4; nt++) {
        float p0 = __builtin_amdgcn_exp2f(st[nt][0] - m_i);
        float p1 = __builtin_amdgcn_exp2f(st[nt][1] - m_i);
        float p2 = __builtin_amdgcn_exp2f(st[nt][2] - m_i);
        float p3 = __builtin_amdgcn_exp2f(st[nt][3] - m_i);
        rs += p0 + p1 + p2 + p3;
        pk[nt] = pack4bf(p0, p1, p2, p3);
    }
    l_i += rs;  // per-lane partial; reduced across quads at epilogue
}

// ---------------------------------------------------------------- fused convert
__global__ __launch_bounds__(256) void convert_all(const float* __restrict__ x,
                                                   const float* __restrict__ wq,
                                                   const float* __restrict__ wk,
                                                   const float* __restrict__ wv,
                                                   const float* __restrict__ wo,
                                                   unsigned short* __restrict__ xb,
                                                   unsigned short* __restrict__ wqkvT,
                                                   unsigned short* __restrict__ woT) {
    __shared__ float Ls[64][65];
    const int bid = blockIdx.x;
    if (bid < 3072) {
        int i = bid * 256 + threadIdx.x;
        float4 v = ((const float4*)x)[i];
        ushort4 o = {f2bf(v.x), f2bf(v.y), f2bf(v.z), f2bf(v.w)};
        ((ushort4*)xb)[i] = o;
        return;
    }
    const int idx = bid - 3072;
    const int z = idx / 144;
    const int bx = (idx % 144) / 12, by = idx % 12;
    const float* W = (z == 0) ? wq : (z == 1) ? wk : (z == 2) ? wv : wo;
    unsigned short* dst = (z < 3) ? (wqkvT + (size_t)z * EMB * EMB) : woT;
    const int k0 = bx * 64, n0 = by * 64;
    const int r = threadIdx.x >> 2, c0 = (threadIdx.x & 3) * 16;
    for (int j = 0; j < 16; j += 4) {
        float4 v = *(const float4*)&W[(size_t)(k0 + r) * EMB + n0 + c0 + j];
        Ls[r][c0 + j] = v.x;
        Ls[r][c0 + j + 1] = v.y;
        Ls[r][c0 + j + 2] = v.z;
        Ls[r][c0 + j + 3] = v.w;
    }
    __syncthreads();
    unsigned short tmp[16];
    for (int j = 0; j < 16; j++) tmp[j] = f2bf(Ls[c0 + j][r]);
    *(uint4*)&dst[(size_t)(n0 + r) * EMB + k0 + c0] = *(uint4*)tmp;
    *(uint4*)&dst[(size_t)(n0 + r) * EMB + k0 + c0 + 8] = *(uint4*)(tmp + 8);
}

// ---------------------------------------------------------------- 64x128 QKV GEMM
__global__ __launch_bounds__(256) void gemm_qkv(const unsigned short* __restrict__ A,
                                                const unsigned short* __restrict__ Bt,
                                                const float* __restrict__ b0p,
                                                const float* __restrict__ b1p,
                                                const float* __restrict__ b2p,
                                                unsigned short* __restrict__ QKb,
                                                unsigned short* __restrict__ Vtb) {
    __shared__ __align__(16) unsigned short SMEM[12288];  // As[2]@0/2048, Bs[2]@4096/8192
    const int tid = threadIdx.x;
    const int wave = tid >> 6, lane = tid & 63, quad = lane >> 4, l16 = lane & 15;
    const int m0 = blockIdx.x * 64, n0 = blockIdx.y * 128;
    const int wm = (wave >> 1) * 32, wn = (wave & 1) * 64;
    const int lrow = lane >> 2, lcol = (lane & 3) * 8;

    f32x4 acc[2][4] = {};

    load_lds16(&A[(size_t)(m0 + wave * 16 + lrow) * EMB + lcol], &SMEM[wave * 512]);
    for (int t = 0; t < 2; t++) {
        int row = wave * 32 + t * 16 + lrow;
        load_lds16(&Bt[(size_t)(n0 + row) * EMB + lcol], &SMEM[4096 + (wave * 2 + t) * 512]);
    }
    int buf = 0;
    for (int k0 = 0; k0 < EMB; k0 += 32) {
        __syncthreads();
        if (k0 + 32 < EMB) {
            unsigned short* A_ = &SMEM[(buf ^ 1) * 2048];
            unsigned short* B_ = &SMEM[4096 + (buf ^ 1) * 4096];
            load_lds16(&A[(size_t)(m0 + wave * 16 + lrow) * EMB + k0 + 32 + lcol], &A_[wave * 512]);
            for (int t = 0; t < 2; t++) {
                int row = wave * 32 + t * 16 + lrow;
                load_lds16(&Bt[(size_t)(n0 + row) * EMB + k0 + 32 + lcol], &B_[(wave * 2 + t) * 512]);
            }
        }
        const unsigned short* A_ = &SMEM[buf * 2048];
        const unsigned short* B_ = &SMEM[4096 + buf * 4096];
        short8 a[2], b[4];
        for (int i = 0; i < 2; i++) a[i] = *(const short8*)&A_[(wm + i * 16 + l16) * 32 + quad * 8];
        for (int j = 0; j < 4; j++) b[j] = *(const short8*)&B_[(wn + j * 16 + l16) * 32 + quad * 8];
        for (int i = 0; i < 2; i++)
            for (int j = 0; j < 4; j++) acc[i][j] = mfma32(a[i], b[j], acc[i][j]);
        buf ^= 1;
    }

    const int z = n0 / EMB;  // block-uniform: 0=Q, 1=K, 2=V
    if (z < 2) {
        const float* bias = z ? b1p : b0p;
        const float sc = z ? 1.0f : QSCALE;
        for (int i = 0; i < 2; i++)
            for (int j = 0; j < 4; j++) {
                int mbase = m0 + wm + i * 16 + quad * 4;
                int n = n0 + wn + j * 16 + l16;  // 0..1535 natural col
                float bv = bias[n - z * EMB];
                for (int r = 0; r < 4; r++)
                    QKb[(size_t)(mbase + r) * 1536 + n] = f2bf((acc[i][j][r] + bv) * sc);
            }
    } else {
        // V^T epilogue for 64-row tiles (SMEM stride 72 ush ≡ 4 mod 32: conflict-free)
        const int nn = n0 + wn + l16 - 2 * EMB;
        for (int j = 0; j < 4; j++) {
            __syncthreads();
            const float bv = b2p[nn + j * 16];
            const int nloc = (wave & 1) * 16 + l16;
            for (int i = 0; i < 2; i++) {
                ushort4 pk;
                pk.x = f2bf(acc[i][j][0] + bv);
                pk.y = f2bf(acc[i][j][1] + bv);
                pk.z = f2bf(acc[i][j][2] + bv);
                pk.w = f2bf(acc[i][j][3] + bv);
                *(ushort4*)&SMEM[nloc * 72 + wm + i * 16 + quad * 4] = pk;
            }
            __syncthreads();
            const int nl = tid >> 3, c = tid & 7;
            const int ng = (nl >> 4) * 64 + j * 16 + (nl & 15) + n0 - 2 * EMB;
            const int hh = ng >> 6, dd = ng & 63;
            unsigned short* dst = &Vtb[(size_t)(hh * HD + dd) * SEQ + m0];
            *(uint4*)&dst[c * 8] = *(uint4*)&SMEM[nl * 72 + c * 8];
        }
    }
}

// ---------------------------------------------------------------- 64x64 out-proj GEMM
__global__ __launch_bounds__(256) void gemm_out(const unsigned short* __restrict__ A,
                                                const unsigned short* __restrict__ Bt,
                                                const float* __restrict__ bias,
                                                float* __restrict__ outp) {
    __shared__ __align__(16) unsigned short SMEM[8192];  // As[2]@0/2048, Bs[2]@4096/6144
    const int tid = threadIdx.x;
    const int wave = tid >> 6, lane = tid & 63, quad = lane >> 4, l16 = lane & 15;
    const int m0 = blockIdx.x * 64, n0 = blockIdx.y * 64;
    const int wm = (wave >> 1) * 32, wn = (wave & 1) * 32;
    const int lrow = lane >> 2, lcol = (lane & 3) * 8;

    f32x4 acc[2][2] = {};

    load_lds16(&A[(size_t)(m0 + wave * 16 + lrow) * EMB + lcol], &SMEM[wave * 512]);
    load_lds16(&Bt[(size_t)(n0 + wave * 16 + lrow) * EMB + lcol], &SMEM[4096 + wave * 512]);
    int buf = 0;
    for (int k0 = 0; k0 < EMB; k0 += 32) {
        __syncthreads();
        if (k0 + 32 < EMB) {
            unsigned short* A_ = &SMEM[(buf ^ 1) * 2048];
            unsigned short* B_ = &SMEM[4096 + (buf ^ 1) * 2048];
            load_lds16(&A[(size_t)(m0 + wave * 16 + lrow) * EMB + k0 + 32 + lcol], &A_[wave * 512]);
            load_lds16(&Bt[(size_t)(n0 + wave * 16 + lrow) * EMB + k0 + 32 + lcol], &B_[wave * 512]);
        }
        const unsigned short* A_ = &SMEM[buf * 2048];
        const unsigned short* B_ = &SMEM[4096 + buf * 2048];
        short8 a[2], b[2];
        for (int i = 0; i < 2; i++) a[i] = *(const short8*)&A_[(wm + i * 16 + l16) * 32 + quad * 8];
        for (int j = 0; j < 2; j++) b[j] = *(const short8*)&B_[(wn + j * 16 + l16) * 32 + quad * 8];
        for (int i = 0; i < 2; i++)
            for (int j = 0; j < 2; j++) acc[i][j] = mfma32(a[i], b[j], acc[i][j]);
        buf ^= 1;
    }

    for (int i = 0; i < 2; i++)
        for (int j = 0; j < 2; j++) {
            int mbase = m0 + wm + i * 16 + quad * 4;
            int n = n0 + wn + j * 16 + l16;
            float bv = bias[n];
            for (int r = 0; r < 4; r++) outp[(size_t)(mbase + r) * EMB + n] = acc[i][j][r] + bv;
        }
}

// ---------------------------------------------------------------- attention
// Final configuration (R20, best measured total 180.6 us): TRIPLE-BUFFERED
// K/V (48 KB LDS), 1 barrier per 64-k tile, software-pipelined
// SM(t) || QK(t+1) || PV(t). 816 blocks = 12 heads x 68 chunks; 256 threads
// = 4 waves x 32 q-rows (2 fragment sets/wave). (256,3) — NEVER (256,4):
// hipcc maps the 4th tier to a 64-VGPR cap -> catastrophic spill (x2 measured).
__global__ __launch_bounds__(256, 3) void attn_kernel(const unsigned short* __restrict__ QKb,
                                                      const unsigned short* __restrict__ Vtb,
                                                      unsigned short* __restrict__ ctxb,
                                                      unsigned short* __restrict__ Op,
                                                      float* __restrict__ mArr,
                                                      float* __restrict__ lArr) {
    __shared__ __align__(16) unsigned short Ks3[3][64 * 64];  // 24 KB
    __shared__ __align__(16) unsigned short Vs3[3][64 * 64];  // 24 KB

    const int bid = blockIdx.x;
    const int h = bid % HEADS;
    const int r2 = 67 - bid / HEADS;  // big i128 (long chunks) first
    int i128, ch, nch;
    if (r2 < 10) {
        i128 = r2; ch = 0; nch = 1;
    } else if (r2 < 30) {
        int t = r2 - 10; i128 = 10 + (t >> 1); ch = t & 1; nch = 2;
    } else if (r2 < 60) {
        int t = r2 - 30; i128 = 20 + t / 3; ch = t % 3; nch = 3;
    } else {
        int t = r2 - 60; i128 = 30 + (t >> 2); ch = t & 3; nch = 4;
    }
    const int T = 2 * i128 + 2;
    const int kb = ch * T / nch;
    const int ke = (ch + 1) * T / nch - 1;
    const int qbase = i128 * 128;
    const int tid = threadIdx.x;
    const int wave = tid >> 6, lane = tid & 63, quad = lane >> 4, l16 = lane & 15;

    const unsigned short* Qg = QKb + (size_t)h * HD;          // row stride 1536
    const unsigned short* Kg = QKb + (size_t)(EMB + h * HD);  // row stride 1536
    const unsigned short* Vh = Vtb + (size_t)h * HD * SEQ;    // [d][m]

    const int qa = qbase + wave * 32 + l16;  // set a: waves 0..3 cover 128 q-rows
    const int qb = qa + 16;                  // set b
    const short8 bQ0a = *(const short8*)&Qg[(size_t)qa * 1536 + quad * 8];
    const short8 bQ1a = *(const short8*)&Qg[(size_t)qa * 1536 + 32 + quad * 8];
    const short8 bQ0b = *(const short8*)&Qg[(size_t)qb * 1536 + quad * 8];
    const short8 bQ1b = *(const short8*)&Qg[(size_t)qb * 1536 + 32 + quad * 8];

    const int row = tid >> 2, t4 = tid & 3;  // 256 threads: 64 rows x 4 chunks
    const int swk = row & 7, swv = row & 15;

    f32x4 Oa[4] = {}, Ob[4] = {};
    float m_a = -3.0e38f, l_a = 0.f;
    float m_b = -3.0e38f, l_b = 0.f;

    uint4 kr0, kr1, vr0, vr1;

    // ---- prologue: stage tiles kb, kb+1; keep tile kb+2 in regs
    {
        const unsigned short* kp = &Kg[(size_t)(kb * 64 + row) * 1536];
        kr0 = *(const uint4*)&kp[(2 * t4) * 8];
        kr1 = *(const uint4*)&kp[(2 * t4 + 1) * 8];
        const unsigned short* vp = &Vh[(size_t)row * SEQ + kb * 64];
        vr0 = *(const uint4*)&vp[t4 * 16];
        vr1 = *(const uint4*)&vp[t4 * 16 + 8];
        unsigned short* Kd = &Ks3[kb % 3][0];
        unsigned short* Vd = &Vs3[kb % 3][0];
        *(uint4*)&Kd[row * 64 + ((2 * t4) ^ swk) * 8] = kr0;
        *(uint4*)&Kd[row * 64 + ((2 * t4 + 1) ^ swk) * 8] = kr1;
        *(uint2*)&Vd[row * 64 + ((4 * t4) ^ swv) * 4] = ((const uint2*)&vr0)[0];
        *(uint2*)&Vd[row * 64 + ((4 * t4 + 1) ^ swv) * 4] = ((const uint2*)&vr0)[1];
        *(uint2*)&Vd[row * 64 + ((4 * t4 + 2) ^ swv) * 4] = ((const uint2*)&vr1)[0];
        *(uint2*)&Vd[row * 64 + ((4 * t4 + 3) ^ swv) * 4] = ((const uint2*)&vr1)[1];
    }
    if (kb + 1 <= ke) {
        const int nb = (kb + 1) * 64;
        const unsigned short* kp = &Kg[(size_t)(nb + row) * 1536];
        kr0 = *(const uint4*)&kp[(2 * t4) * 8];
        kr1 = *(const uint4*)&kp[(2 * t4 + 1) * 8];
        const unsigned short* vp = &Vh[(size_t)row * SEQ + nb];
        vr0 = *(const uint4*)&vp[t4 * 16];
        vr1 = *(const uint4*)&vp[t4 * 16 + 8];
        unsigned short* Kd = &Ks3[(kb + 1) % 3][0];
        unsigned short* Vd = &Vs3[(kb + 1) % 3][0];
        *(uint4*)&Kd[row * 64 + ((2 * t4) ^ swk) * 8] = kr0;
        *(uint4*)&Kd[row * 64 + ((2 * t4 + 1) ^ swk) * 8] = kr1;
        *(uint2*)&Vd[row * 64 + ((4 * t4) ^ swv) * 4] = ((const uint2*)&vr0)[0];
        *(uint2*)&Vd[row * 64 + ((4 * t4 + 1) ^ swv) * 4] = ((const uint2*)&vr0)[1];
        *(uint2*)&Vd[row * 64 + ((4 * t4 + 2) ^ swv) * 4] = ((const uint2*)&vr1)[0];
        *(uint2*)&Vd[row * 64 + ((4 * t4 + 3) ^ swv) * 4] = ((const uint2*)&vr1)[1];
    }
    if (kb + 2 <= ke) {  // tile kb+2 -> regs only
        const int nb = (kb + 2) * 64;
        const unsigned short* kp = &Kg[(size_t)(nb + row) * 1536];
        kr0 = *(const uint4*)&kp[(2 * t4) * 8];
        kr1 = *(const uint4*)&kp[(2 * t4 + 1) * 8];
        const unsigned short* vp = &Vh[(size_t)row * SEQ + nb];
        vr0 = *(const uint4*)&vp[t4 * 16];
        vr1 = *(const uint4*)&vp[t4 * 16 + 8];
    }
    __syncthreads();

    const int qw = qbase + wave * 32 + 31;  // wave's last causal q-row
    const int swr = l16 & 7;

    // prime QK(kb) -> sa/sb
    f32x4 sa[4], sb[4];
    if (kb * 64 <= qw) {
        const unsigned short* Kc = &Ks3[kb % 3][0];
        for (int nt = 0; nt < 4; nt++) {
            short8 aK0 = *(const short8*)&Kc[(nt * 16 + l16) * 64 + (quad ^ swr) * 8];
            short8 aK1 = *(const short8*)&Kc[(nt * 16 + l16) * 64 + ((quad + 4) ^ swr) * 8];
            f32x4 za = {};
            za = mfma32(aK0, bQ0a, za);
            za = mfma32(aK1, bQ1a, za);
            sa[nt] = za;
            f32x4 zb = {};
            zb = mfma32(aK0, bQ0b, zb);
            zb = mfma32(aK1, bQ1b, zb);
            sb[nt] = zb;
        }
        if (kb * 64 + 63 > qbase + wave * 32) {
            for (int nt = 0; nt < 4; nt++)
                for (int r = 0; r < 4; r++) {
                    const int kk = kb * 64 + nt * 16 + quad * 4 + r;
                    if (kk > qa) sa[nt][r] = -INFINITY;
                    if (kk > qb) sb[nt][r] = -INFINITY;
                }
        }
    }

    int b0 = kb % 3;  // buffer of tile kt
    for (int kt = kb; kt <= ke; kt++) {
        const int b1 = (b0 == 2) ? 0 : b0 + 1;  // tile kt+1
        const int b2 = (b1 == 2) ? 0 : b1 + 1;  // tile kt+2

        __syncthreads();  // stage(kt+1) visible; all waves past PV(kt-1)

        if (kt + 2 <= ke) {
            unsigned short* Kd = &Ks3[b2][0];
            unsigned short* Vd = &Vs3[b2][0];
            *(uint4*)&Kd[row * 64 + ((2 * t4) ^ swk) * 8] = kr0;
            *(uint4*)&Kd[row * 64 + ((2 * t4 + 1) ^ swk) * 8] = kr1;
            *(uint2*)&Vd[row * 64 + ((4 * t4) ^ swv) * 4] = ((const uint2*)&vr0)[0];
            *(uint2*)&Vd[row * 64 + ((4 * t4 + 1) ^ swv) * 4] = ((const uint2*)&vr0)[1];
            *(uint2*)&Vd[row * 64 + ((4 * t4 + 2) ^ swv) * 4] = ((const uint2*)&vr1)[0];
            *(uint2*)&Vd[row * 64 + ((4 * t4 + 3) ^ swv) * 4] = ((const uint2*)&vr1)[1];
            if (kt + 3 <= ke) {
                const int nb = (kt + 3) * 64;
                const unsigned short* kp = &Kg[(size_t)(nb + row) * 1536];
                kr0 = *(const uint4*)&kp[(2 * t4) * 8];
                kr1 = *(const uint4*)&kp[(2 * t4 + 1) * 8];
                const unsigned short* vp = &Vh[(size_t)row * SEQ + nb];
                vr0 = *(const uint4*)&vp[t4 * 16];
                vr1 = *(const uint4*)&vp[t4 * 16 + 8];
            }
        }

        const int kbase = kt * 64;
        const bool cur = (kbase <= qw);

        short4v pka[4], pkb[4];
        if (cur) {
            softmax_q(sa, m_a, l_a, Oa, pka);
            softmax_q(sb, m_b, l_b, Ob, pkb);
        }

        const int kn = kbase + 64;
        if (kt < ke && kn <= qw) {
            const unsigned short* Kc = &Ks3[b1][0];
            for (int nt = 0; nt < 4; nt++) {
                short8 aK0 = *(const short8*)&Kc[(nt * 16 + l16) * 64 + (quad ^ swr) * 8];
                short8 aK1 = *(const short8*)&Kc[(nt * 16 + l16) * 64 + ((quad + 4) ^ swr) * 8];
                f32x4 za = {};
                za = mfma32(aK0, bQ0a, za);
                za = mfma32(aK1, bQ1a, za);
                sa[nt] = za;
                f32x4 zb = {};
                zb = mfma32(aK0, bQ0b, zb);
                zb = mfma32(aK1, bQ1b, zb);
                sb[nt] = zb;
            }
            if (kn + 63 > qbase + wave * 32) {
                for (int nt = 0; nt < 4; nt++)
                    for (int r = 0; r < 4; r++) {
                        const int kk = kn + nt * 16 + quad * 4 + r;
                        if (kk > qa) sa[nt][r] = -INFINITY;
                        if (kk > qb) sb[nt][r] = -INFINITY;
                    }
            }
        }

        if (cur) {
            const unsigned short* Vc = &Vs3[b0][0];
            for (int dt = 0; dt < 4; dt++)
                for (int nt = 0; nt < 4; nt++) {
                    short4v av =
                        *(const short4v*)&Vc[(dt * 16 + l16) * 64 + ((4 * nt + quad) ^ l16) * 4];
                    Oa[dt] = mfma16(av, pka[nt], Oa[dt]);
                    Ob[dt] = mfma16(av, pkb[nt], Ob[dt]);
                }
        }

        b0 = b1;
    }

    // deferred cross-lane l reduction (m is quad-uniform by construction)
    l_a += __shfl_xor(l_a, 16);
    l_a += __shfl_xor(l_a, 32);
    l_b += __shfl_xor(l_b, 16);
    l_b += __shfl_xor(l_b, 32);

    const int qla = wave * 32 + l16;  // 0..127 across 4 waves (set a)
    const int qlb = qla + 16;         // set b
    if (nch == 1) {
        const float ia = 1.f / l_a, ib = 1.f / l_b;
        for (int dt = 0; dt < 4; dt++) {
            ushort4 oa, ob;
            oa.x = f2bf(Oa[dt][0] * ia);
            oa.y = f2bf(Oa[dt][1] * ia);
            oa.z = f2bf(Oa[dt][2] * ia);
            oa.w = f2bf(Oa[dt][3] * ia);
            ob.x = f2bf(Ob[dt][0] * ib);
            ob.y = f2bf(Ob[dt][1] * ib);
            ob.z = f2bf(Ob[dt][2] * ib);
            ob.w = f2bf(Ob[dt][3] * ib);
            *(ushort4*)&ctxb[(size_t)qa * EMB + h * HD + dt * 16 + quad * 4] = oa;
            *(ushort4*)&ctxb[(size_t)qb * EMB + h * HD + dt * 16 + quad * 4] = ob;
        }
    } else {
        if (ch == 0) {
            for (int dt = 0; dt < 4; dt++) {
                ushort4 oa, ob;
                oa.x = f2bf(Oa[dt][0]);
                oa.y = f2bf(Oa[dt][1]);
                oa.z = f2bf(Oa[dt][2]);
                oa.w = f2bf(Oa[dt][3]);
                ob.x = f2bf(Ob[dt][0]);
                ob.y = f2bf(Ob[dt][1]);
                ob.z = f2bf(Ob[dt][2]);
                ob.w = f2bf(Ob[dt][3]);
                *(ushort4*)&ctxb[(size_t)qa * EMB + h * HD + dt * 16 + quad * 4] = oa;
                *(ushort4*)&ctxb[(size_t)qb * EMB + h * HD + dt * 16 + quad * 4] = ob;
            }
        } else {
            const int pid = pid_of(h, i128, ch);
            for (int dt = 0; dt < 4; dt++) {
                ushort4 oa, ob;
                oa.x = f2bf(Oa[dt][0]);
                oa.y = f2bf(Oa[dt][1]);
                oa.z = f2bf(Oa[dt][2]);
                oa.w = f2bf(Oa[dt][3]);
                ob.x = f2bf(Ob[dt][0]);
                ob.y = f2bf(Ob[dt][1]);
                ob.z = f2bf(Ob[dt][2]);
                ob.w = f2bf(Ob[dt][3]);
                *(ushort4*)&Op[(size_t)pid * 8192 + qla * 64 + dt * 16 + quad * 4] = oa;
                *(ushort4*)&Op[(size_t)pid * 8192 + qlb * 64 + dt * 16 + quad * 4] = ob;
            }
        }
        if (quad == 0) {
            const int mlb = ((h * 32 + i128) * 4 + ch) * 128;
            mArr[mlb + qla] = m_a;
            lArr[mlb + qla] = l_a;
            mArr[mlb + qlb] = m_b;
            lArr[mlb + qlb] = l_b;
        }
    }
}

// ---------------------------------------------------------------- merge (i128>=10)
__global__ __launch_bounds__(256) void merge_kernel(const unsigned short* __restrict__ Op,
                                                    const float* __restrict__ mArr,
                                                    const float* __restrict__ lArr,
                                                    unsigned short* __restrict__ ctxb) {
    const int gid = blockIdx.x;  // 0..263
    const int h = gid % HEADS;
    const int i128 = 10 + gid / HEADS;
    const int nch = (i128 < 20) ? 2 : (i128 < 30) ? 3 : 4;
    const int q = threadIdx.x >> 1, d0 = (threadIdx.x & 1) * 32;
    const int mlbase = (h * 32 + i128) * 4;

    float mc[4], lc[4];
    for (int c = 0; c < nch; c++) {
        mc[c] = mArr[(mlbase + c) * 128 + q];
        lc[c] = lArr[(mlbase + c) * 128 + q];
    }
    float M = mc[0];
    for (int c = 1; c < nch; c++) M = fmaxf(M, mc[c]);
    float w[4], L = 0.f;
    for (int c = 0; c < nch; c++) {
        w[c] = __builtin_amdgcn_exp2f(mc[c] - M);
        L += w[c] * lc[c];
    }
    const float inv = 1.f / L;
    for (int c = 0; c < nch; c++) w[c] *= inv;

    unsigned short* dst = &ctxb[(size_t)(i128 * 128 + q) * EMB + h * HD + d0];
    for (int jj = 0; jj < 32; jj += 8) {
        uint4 u0 = *(const uint4*)&dst[jj];  // chunk0 (unnormalized) in place
        float f[8];
        const unsigned short* p0 = (const unsigned short*)&u0;
        for (int t = 0; t < 8; t++)
            f[t] = w[0] * __builtin_bit_cast(float, (unsigned int)p0[t] << 16);
        for (int c = 1; c < nch; c++) {
            const int pid = pid_of(h, i128, c);
            uint4 u = *(const uint4*)&Op[(size_t)pid * 8192 + q * 64 + d0 + jj];
            const unsigned short* p = (const unsigned short*)&u;
            for (int t = 0; t < 8; t++)
                f[t] += w[c] * __builtin_bit_cast(float, (unsigned int)p[t] << 16);
        }
        unsigned short o[8];
        for (int t = 0; t < 8; t++) o[t] = f2bf(f[t]);
        *(uint4*)&dst[jj] = *(uint4*)o;
    }
}

// ---------------------------------------------------------------- launch
extern "C" void kernel_launch(void* const* d_in, const int* in_sizes, int n_in,
                              void* d_out, int out_size, void* d_ws, size_t ws_size,
                              hipStream_t stream) {
    const float* x = (const float*)d_in[0];
    const float* wq = (const float*)d_in[1];
    const float* bq = (const float*)d_in[2];
    const float* wk = (const float*)d_in[3];
    const float* bk = (const float*)d_in[4];
    const float* wv = (const float*)d_in[5];
    const float* bv = (const float*)d_in[6];
    const float* wo = (const float*)d_in[7];
    const float* bo = (const float*)d_in[8];

    unsigned short* ws = (unsigned short*)d_ws;
    unsigned short* xb = ws;                          // 3,145,728 ush
    unsigned short* wqkvT = xb + SEQ * EMB;           // 1,769,472
    unsigned short* woT = wqkvT + 3 * EMB * EMB;      // 589,824
    unsigned short* QKb = woT + EMB * EMB;            // 4096*1536
    unsigned short* Vtb = QKb + (size_t)SEQ * 1536;   // 3,145,728
    unsigned short* ctxb = Vtb + HEADS * SEQ * HD;    // 3,145,728
    // attn-phase scratch aliases xb+wqkvT (dead after gemm_qkv):
    // Op 432*8192 = 3,538,944 ush; mArr/lArr 196,608 f32 each -> ends 4,325,376
    unsigned short* Op = xb;
    float* mArr = (float*)(ws + 3538944);
    float* lArr = mArr + 196608;

    convert_all<<<dim3(3072 + 576), 256, 0, stream>>>(x, wq, wk, wv, wo, xb, wqkvT, woT);
    gemm_qkv<<<dim3(SEQ / 64, 3 * EMB / 128), 256, 0, stream>>>(
        xb, wqkvT, bq, bk, bv, QKb, Vtb);
    attn_kernel<<<dim3(12 * 68), 256, 0, stream>>>(QKb, Vtb, ctxb, Op, mArr, lArr);
    merge_kernel<<<dim3(264), 256, 0, stream>>>(Op, mArr, lArr, ctxb);
    gemm_out<<<dim3(SEQ / 64, EMB / 64), 256, 0, stream>>>(ctxb, woT, bo, (float*)d_out);
}

// Round 15
// 179.389 us; speedup vs baseline: 1.2210x; 1.0083x over previous
//
#include <hip/hip_runtime.h>
#include <stdint.h>

#define SEQ 4096
#define EMB 768
#define HEADS 12
#define HD 64

typedef __attribute__((ext_vector_type(8))) short short8;
typedef __attribute__((ext_vector_type(4))) short short4v;
typedef __attribute__((ext_vector_type(8))) __bf16 bf16x8;
typedef __attribute__((ext_vector_type(4))) __bf16 bf16x4;
typedef __attribute__((ext_vector_type(4))) float f32x4;

// scale * log2(e) folded into Q: (1/sqrt(64)) * 1.4426950408889634
#define QSCALE 0.18033688011112043f

static __device__ __forceinline__ unsigned short f2bf(float f) {
    unsigned int u = __builtin_bit_cast(unsigned int, f);
    unsigned int r = 0x7fffu + ((u >> 16) & 1u);
    u += r;
    return (unsigned short)(u >> 16);
}

static __device__ __forceinline__ f32x4 mfma32(short8 a, short8 b, f32x4 c) {
    return __builtin_amdgcn_mfma_f32_16x16x32_bf16(
        __builtin_bit_cast(bf16x8, a), __builtin_bit_cast(bf16x8, b), c, 0, 0, 0);
}

static __device__ __forceinline__ f32x4 mfma16(short4v a, short4v b, f32x4 c) {
#if __has_builtin(__builtin_amdgcn_mfma_f32_16x16x16_bf16)
    return __builtin_amdgcn_mfma_f32_16x16x16_bf16(
        __builtin_bit_cast(bf16x4, a), __builtin_bit_cast(bf16x4, b), c, 0, 0, 0);
#else
    return __builtin_amdgcn_mfma_f32_16x16x16bf16_1k(a, b, c, 0, 0, 0);
#endif
}

static __device__ __forceinline__ short4v pack4bf(float a, float b, float c, float d) {
#if __has_builtin(__builtin_amdgcn_cvt_pk_bf16_f32)
    typedef __attribute__((ext_vector_type(2))) __bf16 bf16x2;
    bf16x2 lo = __builtin_amdgcn_cvt_pk_bf16_f32(a, b);
    bf16x2 hi = __builtin_amdgcn_cvt_pk_bf16_f32(c, d);
    uint2 u = {__builtin_bit_cast(unsigned int, lo), __builtin_bit_cast(unsigned int, hi)};
    return __builtin_bit_cast(short4v, u);
#else
    short4v p;
    p[0] = (short)f2bf(a); p[1] = (short)f2bf(b);
    p[2] = (short)f2bf(c); p[3] = (short)f2bf(d);
    return p;
#endif
}

static __device__ __forceinline__ void load_lds16(const void* g, void* l) {
    __builtin_amdgcn_global_load_lds(
        (const __attribute__((address_space(1))) unsigned int*)(uintptr_t)g,
        (__attribute__((address_space(3))) unsigned int*)(uintptr_t)l, 16, 0, 0);
}

// partial-id for (h, i128, ch>=1); 36 slots/head, 432 total
static __device__ __forceinline__ int pid_of(int h, int i128, int ch) {
    int b = (i128 < 20) ? (i128 - 10)
                        : (i128 < 30 ? 10 + (i128 - 20) * 2 : 30 + (i128 - 30) * 3);
    return h * 36 + b + (ch - 1);
}

// online-softmax step over one 64-k tile held as st[4] (S^T layout).
// Common path is LANE-LOCAL only (15-op fmax tree). Cross-quad reduce +
// rescale live inside the rare defer-max branch. m_i stays quad-uniform by
// induction, so P fed to the k-spanning PV MFMA is consistently normalized.
static __device__ __forceinline__ void softmax_q(f32x4* st, float& m_i, float& l_i,
                                                 f32x4* O, short4v* pk) {
    float t0 = fmaxf(fmaxf(st[0][0], st[0][1]), fmaxf(st[0][2], st[0][3]));
    float t1 = fmaxf(fmaxf(st[1][0], st[1][1]), fmaxf(st[1][2], st[1][3]));
    float t2 = fmaxf(fmaxf(st[2][0], st[2][1]), fmaxf(st[2][2], st[2][3]));
    float t3 = fmaxf(fmaxf(st[3][0], st[3][1]), fmaxf(st[3][2], st[3][3]));
    float mx = fmaxf(fmaxf(t0, t1), fmaxf(t2, t3));  // this lane's 16 values
    if (__ballot(mx > m_i + 5.0f)) {  // rare after warm-up
        mx = fmaxf(mx, __shfl_xor(mx, 16));
        mx = fmaxf(mx, __shfl_xor(mx, 32));  // per-q (cross-quad) max
        const bool inc = mx > m_i;
        const float mn = inc ? mx : m_i;
        const float alpha = __builtin_amdgcn_exp2f(m_i - mn);
        m_i = mn;
        l_i *= alpha;
        for (int dt = 0; dt < 4; dt++)
            for (int r = 0; r < 4; r++) O[dt][r] *= alpha;
    }
    float rs = 0.f;
    for (int nt = 0; nt < 4; nt++) {
        float p0 = __builtin_amdgcn_exp2f(st[nt][0] - m_i);
        float p1 = __builtin_amdgcn_exp2f(st[nt][1] - m_i);
        float p2 = __builtin_amdgcn_exp2f(st[nt][2] - m_i);
        float p3 = __builtin_amdgcn_exp2f(st[nt][3] - m_i);
        rs += p0 + p1 + p2 + p3;
        pk[nt] = pack4bf(p0, p1, p2, p3);
    }
    l_i += rs;  // per-lane partial; reduced across quads at epilogue
}

// ---------------------------------------------------------------- fused convert
__global__ __launch_bounds__(256) void convert_all(const float* __restrict__ x,
                                                   const float* __restrict__ wq,
                                                   const float* __restrict__ wk,
                                                   const float* __restrict__ wv,
                                                   const float* __restrict__ wo,
                                                   unsigned short* __restrict__ xb,
                                                   unsigned short* __restrict__ wqkvT,
                                                   unsigned short* __restrict__ woT) {
    __shared__ float Ls[64][65];
    const int bid = blockIdx.x;
    if (bid < 3072) {
        int i = bid * 256 + threadIdx.x;
        float4 v = ((const float4*)x)[i];
        ushort4 o = {f2bf(v.x), f2bf(v.y), f2bf(v.z), f2bf(v.w)};
        ((ushort4*)xb)[i] = o;
        return;
    }
    const int idx = bid - 3072;
    const int z = idx / 144;
    const int bx = (idx % 144) / 12, by = idx % 12;
    const float* W = (z == 0) ? wq : (z == 1) ? wk : (z == 2) ? wv : wo;
    unsigned short* dst = (z < 3) ? (wqkvT + (size_t)z * EMB * EMB) : woT;
    const int k0 = bx * 64, n0 = by * 64;
    const int r = threadIdx.x >> 2, c0 = (threadIdx.x & 3) * 16;
    for (int j = 0; j < 16; j += 4) {
        float4 v = *(const float4*)&W[(size_t)(k0 + r) * EMB + n0 + c0 + j];
        Ls[r][c0 + j] = v.x;
        Ls[r][c0 + j + 1] = v.y;
        Ls[r][c0 + j + 2] = v.z;
        Ls[r][c0 + j + 3] = v.w;
    }
    __syncthreads();
    unsigned short tmp[16];
    for (int j = 0; j < 16; j++) tmp[j] = f2bf(Ls[c0 + j][r]);
    *(uint4*)&dst[(size_t)(n0 + r) * EMB + k0 + c0] = *(uint4*)tmp;
    *(uint4*)&dst[(size_t)(n0 + r) * EMB + k0 + c0 + 8] = *(uint4*)(tmp + 8);
}

// ---------------------------------------------------------------- 64x128 QKV GEMM (BK=64)
// R25: BK 32 -> 64 via TWO-PANE LDS buffers. Iteration count 24 -> 12: the
// per-step fixed overhead (barrier + DMA drain) — on a kernel profiled at
// MfmaUtil 7% / VALUBusy 23% (R21's variant) — is amortized over 2x work.
// Each pane is a [rows][32] block identical in layout/DMA/fragment pattern
// to the proven conflict-free BK=32 kernel; only the barrier count halves.
// LDS 48 KB (As[2] 2x2048 @0; Bs[2] 2x4096 @8192), occupancy unchanged
// (pinned ~2 blocks/CU from 16-48 KB, measured).
__global__ __launch_bounds__(256) void gemm_qkv(const unsigned short* __restrict__ A,
                                                const unsigned short* __restrict__ Bt,
                                                const float* __restrict__ b0p,
                                                const float* __restrict__ b1p,
                                                const float* __restrict__ b2p,
                                                unsigned short* __restrict__ QKb,
                                                unsigned short* __restrict__ Vtb) {
    __shared__ __align__(16) unsigned short SMEM[24576];  // As[2]@0/4096, Bs[2]@8192/16384
    const int tid = threadIdx.x;
    const int wave = tid >> 6, lane = tid & 63, quad = lane >> 4, l16 = lane & 15;
    const int m0 = blockIdx.x * 64, n0 = blockIdx.y * 128;
    const int wm = (wave >> 1) * 32, wn = (wave & 1) * 64;
    const int lrow = lane >> 2, lcol = (lane & 3) * 8;

    f32x4 acc[2][4] = {};

    for (int p = 0; p < 2; p++) {
        load_lds16(&A[(size_t)(m0 + wave * 16 + lrow) * EMB + p * 32 + lcol],
                   &SMEM[p * 2048 + wave * 512]);
        for (int t = 0; t < 2; t++) {
            int row = wave * 32 + t * 16 + lrow;
            load_lds16(&Bt[(size_t)(n0 + row) * EMB + p * 32 + lcol],
                       &SMEM[8192 + p * 4096 + (wave * 2 + t) * 512]);
        }
    }
    int buf = 0;
    for (int k0 = 0; k0 < EMB; k0 += 64) {
        __syncthreads();  // buf DMA drained; other buf free
        if (k0 + 64 < EMB) {
            unsigned short* A_ = &SMEM[(buf ^ 1) * 4096];
            unsigned short* B_ = &SMEM[8192 + (buf ^ 1) * 8192];
            for (int p = 0; p < 2; p++) {
                load_lds16(&A[(size_t)(m0 + wave * 16 + lrow) * EMB + k0 + 64 + p * 32 + lcol],
                           &A_[p * 2048 + wave * 512]);
                for (int t = 0; t < 2; t++) {
                    int row = wave * 32 + t * 16 + lrow;
                    load_lds16(&Bt[(size_t)(n0 + row) * EMB + k0 + 64 + p * 32 + lcol],
                               &B_[p * 4096 + (wave * 2 + t) * 512]);
                }
            }
        }
        const unsigned short* A_ = &SMEM[buf * 4096];
        const unsigned short* B_ = &SMEM[8192 + buf * 8192];
        for (int p = 0; p < 2; p++) {
            short8 a[2], b[4];
            for (int i = 0; i < 2; i++)
                a[i] = *(const short8*)&A_[p * 2048 + (wm + i * 16 + l16) * 32 + quad * 8];
            for (int j = 0; j < 4; j++)
                b[j] = *(const short8*)&B_[p * 4096 + (wn + j * 16 + l16) * 32 + quad * 8];
            for (int i = 0; i < 2; i++)
                for (int j = 0; j < 4; j++) acc[i][j] = mfma32(a[i], b[j], acc[i][j]);
        }
        buf ^= 1;
    }

    const int z = n0 / EMB;  // block-uniform: 0=Q, 1=K, 2=V
    if (z < 2) {
        const float* bias = z ? b1p : b0p;
        const float sc = z ? 1.0f : QSCALE;
        for (int i = 0; i < 2; i++)
            for (int j = 0; j < 4; j++) {
                int mbase = m0 + wm + i * 16 + quad * 4;
                int n = n0 + wn + j * 16 + l16;  // 0..1535 natural col
                float bv = bias[n - z * EMB];
                for (int r = 0; r < 4; r++)
                    QKb[(size_t)(mbase + r) * 1536 + n] = f2bf((acc[i][j][r] + bv) * sc);
            }
    } else {
        // V^T epilogue for 64-row tiles (SMEM stride 72 ush ≡ 4 mod 32: conflict-free)
        const int nn = n0 + wn + l16 - 2 * EMB;
        for (int j = 0; j < 4; j++) {
            __syncthreads();
            const float bv = b2p[nn + j * 16];
            const int nloc = (wave & 1) * 16 + l16;
            for (int i = 0; i < 2; i++) {
                ushort4 pk;
                pk.x = f2bf(acc[i][j][0] + bv);
                pk.y = f2bf(acc[i][j][1] + bv);
                pk.z = f2bf(acc[i][j][2] + bv);
                pk.w = f2bf(acc[i][j][3] + bv);
                *(ushort4*)&SMEM[nloc * 72 + wm + i * 16 + quad * 4] = pk;
            }
            __syncthreads();
            const int nl = tid >> 3, c = tid & 7;
            const int ng = (nl >> 4) * 64 + j * 16 + (nl & 15) + n0 - 2 * EMB;
            const int hh = ng >> 6, dd = ng & 63;
            unsigned short* dst = &Vtb[(size_t)(hh * HD + dd) * SEQ + m0];
            *(uint4*)&dst[c * 8] = *(uint4*)&SMEM[nl * 72 + c * 8];
        }
    }
}

// ---------------------------------------------------------------- 64x64 out-proj GEMM (BK=64)
// R25: same two-pane BK=64 amortization; 24 -> 12 steps; LDS 32 KB.
__global__ __launch_bounds__(256) void gemm_out(const unsigned short* __restrict__ A,
                                                const unsigned short* __restrict__ Bt,
                                                const float* __restrict__ bias,
                                                float* __restrict__ outp) {
    __shared__ __align__(16) unsigned short SMEM[16384];  // As[2]@0/4096, Bs[2]@8192/12288
    const int tid = threadIdx.x;
    const int wave = tid >> 6, lane = tid & 63, quad = lane >> 4, l16 = lane & 15;
    const int m0 = blockIdx.x * 64, n0 = blockIdx.y * 64;
    const int wm = (wave >> 1) * 32, wn = (wave & 1) * 32;
    const int lrow = lane >> 2, lcol = (lane & 3) * 8;

    f32x4 acc[2][2] = {};

    for (int p = 0; p < 2; p++) {
        load_lds16(&A[(size_t)(m0 + wave * 16 + lrow) * EMB + p * 32 + lcol],
                   &SMEM[p * 2048 + wave * 512]);
        load_lds16(&Bt[(size_t)(n0 + wave * 16 + lrow) * EMB + p * 32 + lcol],
                   &SMEM[8192 + p * 2048 + wave * 512]);
    }
    int buf = 0;
    for (int k0 = 0; k0 < EMB; k0 += 64) {
        __syncthreads();
        if (k0 + 64 < EMB) {
            unsigned short* A_ = &SMEM[(buf ^ 1) * 4096];
            unsigned short* B_ = &SMEM[8192 + (buf ^ 1) * 4096];
            for (int p = 0; p < 2; p++) {
                load_lds16(&A[(size_t)(m0 + wave * 16 + lrow) * EMB + k0 + 64 + p * 32 + lcol],
                           &A_[p * 2048 + wave * 512]);
                load_lds16(&Bt[(size_t)(n0 + wave * 16 + lrow) * EMB + k0 + 64 + p * 32 + lcol],
                           &B_[p * 2048 + wave * 512]);
            }
        }
        const unsigned short* A_ = &SMEM[buf * 4096];
        const unsigned short* B_ = &SMEM[8192 + buf * 4096];
        for (int p = 0; p < 2; p++) {
            short8 a[2], b[2];
            for (int i = 0; i < 2; i++)
                a[i] = *(const short8*)&A_[p * 2048 + (wm + i * 16 + l16) * 32 + quad * 8];
            for (int j = 0; j < 2; j++)
                b[j] = *(const short8*)&B_[p * 2048 + (wn + j * 16 + l16) * 32 + quad * 8];
            for (int i = 0; i < 2; i++)
                for (int j = 0; j < 2; j++) acc[i][j] = mfma32(a[i], b[j], acc[i][j]);
        }
        buf ^= 1;
    }

    for (int i = 0; i < 2; i++)
        for (int j = 0; j < 2; j++) {
            int mbase = m0 + wm + i * 16 + quad * 4;
            int n = n0 + wn + j * 16 + l16;
            float bv = bias[n];
            for (int r = 0; r < 4; r++) outp[(size_t)(mbase + r) * EMB + n] = acc[i][j][r] + bv;
        }
}

// ---------------------------------------------------------------- attention
// Frozen (R20/R24, verified 180.6-180.9 us total): TRIPLE-BUFFERED K/V
// (48 KB LDS), 1 barrier per 64-k tile, software-pipelined
// SM(t) || QK(t+1) || PV(t). 816 blocks = 12 heads x 68 chunks; 256 threads
// = 4 waves x 32 q-rows (2 fragment sets/wave). (256,3) — NEVER (256,4):
// hipcc maps the 4th tier to a 64-VGPR cap -> catastrophic spill (x2 measured).
__global__ __launch_bounds__(256, 3) void attn_kernel(const unsigned short* __restrict__ QKb,
                                                      const unsigned short* __restrict__ Vtb,
                                                      unsigned short* __restrict__ ctxb,
                                                      unsigned short* __restrict__ Op,
                                                      float* __restrict__ mArr,
                                                      float* __restrict__ lArr) {
    __shared__ __align__(16) unsigned short Ks3[3][64 * 64];  // 24 KB
    __shared__ __align__(16) unsigned short Vs3[3][64 * 64];  // 24 KB

    const int bid = blockIdx.x;
    const int h = bid % HEADS;
    const int r2 = 67 - bid / HEADS;  // big i128 (long chunks) first
    int i128, ch, nch;
    if (r2 < 10) {
        i128 = r2; ch = 0; nch = 1;
    } else if (r2 < 30) {
        int t = r2 - 10; i128 = 10 + (t >> 1); ch = t & 1; nch = 2;
    } else if (r2 < 60) {
        int t = r2 - 30; i128 = 20 + t / 3; ch = t % 3; nch = 3;
    } else {
        int t = r2 - 60; i128 = 30 + (t >> 2); ch = t & 3; nch = 4;
    }
    const int T = 2 * i128 + 2;
    const int kb = ch * T / nch;
    const int ke = (ch + 1) * T / nch - 1;
    const int qbase = i128 * 128;
    const int tid = threadIdx.x;
    const int wave = tid >> 6, lane = tid & 63, quad = lane >> 4, l16 = lane & 15;

    const unsigned short* Qg = QKb + (size_t)h * HD;          // row stride 1536
    const unsigned short* Kg = QKb + (size_t)(EMB + h * HD);  // row stride 1536
    const unsigned short* Vh = Vtb + (size_t)h * HD * SEQ;    // [d][m]

    const int qa = qbase + wave * 32 + l16;  // set a: waves 0..3 cover 128 q-rows
    const int qb = qa + 16;                  // set b
    const short8 bQ0a = *(const short8*)&Qg[(size_t)qa * 1536 + quad * 8];
    const short8 bQ1a = *(const short8*)&Qg[(size_t)qa * 1536 + 32 + quad * 8];
    const short8 bQ0b = *(const short8*)&Qg[(size_t)qb * 1536 + quad * 8];
    const short8 bQ1b = *(const short8*)&Qg[(size_t)qb * 1536 + 32 + quad * 8];

    const int row = tid >> 2, t4 = tid & 3;  // 256 threads: 64 rows x 4 chunks
    const int swk = row & 7, swv = row & 15;

    f32x4 Oa[4] = {}, Ob[4] = {};
    float m_a = -3.0e38f, l_a = 0.f;
    float m_b = -3.0e38f, l_b = 0.f;

    uint4 kr0, kr1, vr0, vr1;

    // ---- prologue: stage tiles kb, kb+1; keep tile kb+2 in regs
    {
        const unsigned short* kp = &Kg[(size_t)(kb * 64 + row) * 1536];
        kr0 = *(const uint4*)&kp[(2 * t4) * 8];
        kr1 = *(const uint4*)&kp[(2 * t4 + 1) * 8];
        const unsigned short* vp = &Vh[(size_t)row * SEQ + kb * 64];
        vr0 = *(const uint4*)&vp[t4 * 16];
        vr1 = *(const uint4*)&vp[t4 * 16 + 8];
        unsigned short* Kd = &Ks3[kb % 3][0];
        unsigned short* Vd = &Vs3[kb % 3][0];
        *(uint4*)&Kd[row * 64 + ((2 * t4) ^ swk) * 8] = kr0;
        *(uint4*)&Kd[row * 64 + ((2 * t4 + 1) ^ swk) * 8] = kr1;
        *(uint2*)&Vd[row * 64 + ((4 * t4) ^ swv) * 4] = ((const uint2*)&vr0)[0];
        *(uint2*)&Vd[row * 64 + ((4 * t4 + 1) ^ swv) * 4] = ((const uint2*)&vr0)[1];
        *(uint2*)&Vd[row * 64 + ((4 * t4 + 2) ^ swv) * 4] = ((const uint2*)&vr1)[0];
        *(uint2*)&Vd[row * 64 + ((4 * t4 + 3) ^ swv) * 4] = ((const uint2*)&vr1)[1];
    }
    if (kb + 1 <= ke) {
        const int nb = (kb + 1) * 64;
        const unsigned short* kp = &Kg[(size_t)(nb + row) * 1536];
        kr0 = *(const uint4*)&kp[(2 * t4) * 8];
        kr1 = *(const uint4*)&kp[(2 * t4 + 1) * 8];
        const unsigned short* vp = &Vh[(size_t)row * SEQ + nb];
        vr0 = *(const uint4*)&vp[t4 * 16];
        vr1 = *(const uint4*)&vp[t4 * 16 + 8];
        unsigned short* Kd = &Ks3[(kb + 1) % 3][0];
        unsigned short* Vd = &Vs3[(kb + 1) % 3][0];
        *(uint4*)&Kd[row * 64 + ((2 * t4) ^ swk) * 8] = kr0;
        *(uint4*)&Kd[row * 64 + ((2 * t4 + 1) ^ swk) * 8] = kr1;
        *(uint2*)&Vd[row * 64 + ((4 * t4) ^ swv) * 4] = ((const uint2*)&vr0)[0];
        *(uint2*)&Vd[row * 64 + ((4 * t4 + 1) ^ swv) * 4] = ((const uint2*)&vr0)[1];
        *(uint2*)&Vd[row * 64 + ((4 * t4 + 2) ^ swv) * 4] = ((const uint2*)&vr1)[0];
        *(uint2*)&Vd[row * 64 + ((4 * t4 + 3) ^ swv) * 4] = ((const uint2*)&vr1)[1];
    }
    if (kb + 2 <= ke) {  // tile kb+2 -> regs only
        const int nb = (kb + 2) * 64;
        const unsigned short* kp = &Kg[(size_t)(nb + row) * 1536];
        kr0 = *(const uint4*)&kp[(2 * t4) * 8];
        kr1 = *(const uint4*)&kp[(2 * t4 + 1) * 8];
        const unsigned short* vp = &Vh[(size_t)row * SEQ + nb];
        vr0 = *(const uint4*)&vp[t4 * 16];
        vr1 = *(const uint4*)&vp[t4 * 16 + 8];
    }
    __syncthreads();

    const int qw = qbase + wave * 32 + 31;  // wave's last causal q-row
    const int swr = l16 & 7;

    // prime QK(kb) -> sa/sb
    f32x4 sa[4], sb[4];
    if (kb * 64 <= qw) {
        const unsigned short* Kc = &Ks3[kb % 3][0];
        for (int nt = 0; nt < 4; nt++) {
            short8 aK0 = *(const short8*)&Kc[(nt * 16 + l16) * 64 + (quad ^ swr) * 8];
            short8 aK1 = *(const short8*)&Kc[(nt * 16 + l16) * 64 + ((quad + 4) ^ swr) * 8];
            f32x4 za = {};
            za = mfma32(aK0, bQ0a, za);
            za = mfma32(aK1, bQ1a, za);
            sa[nt] = za;
            f32x4 zb = {};
            zb = mfma32(aK0, bQ0b, zb);
            zb = mfma32(aK1, bQ1b, zb);
            sb[nt] = zb;
        }
        if (kb * 64 + 63 > qbase + wave * 32) {
            for (int nt = 0; nt < 4; nt++)
                for (int r = 0; r < 4; r++) {
                    const int kk = kb * 64 + nt * 16 + quad * 4 + r;
                    if (kk > qa) sa[nt][r] = -INFINITY;
                    if (kk > qb) sb[nt][r] = -INFINITY;
                }
        }
    }

    int b0 = kb % 3;  // buffer of tile kt
    for (int kt = kb; kt <= ke; kt++) {
        const int b1 = (b0 == 2) ? 0 : b0 + 1;  // tile kt+1
        const int b2 = (b1 == 2) ? 0 : b1 + 1;  // tile kt+2

        __syncthreads();  // stage(kt+1) visible; all waves past PV(kt-1)

        if (kt + 2 <= ke) {
            unsigned short* Kd = &Ks3[b2][0];
            unsigned short* Vd = &Vs3[b2][0];
            *(uint4*)&Kd[row * 64 + ((2 * t4) ^ swk) * 8] = kr0;
            *(uint4*)&Kd[row * 64 + ((2 * t4 + 1) ^ swk) * 8] = kr1;
            *(uint2*)&Vd[row * 64 + ((4 * t4) ^ swv) * 4] = ((const uint2*)&vr0)[0];
            *(uint2*)&Vd[row * 64 + ((4 * t4 + 1) ^ swv) * 4] = ((const uint2*)&vr0)[1];
            *(uint2*)&Vd[row * 64 + ((4 * t4 + 2) ^ swv) * 4] = ((const uint2*)&vr1)[0];
            *(uint2*)&Vd[row * 64 + ((4 * t4 + 3) ^ swv) * 4] = ((const uint2*)&vr1)[1];
            if (kt + 3 <= ke) {
                const int nb = (kt + 3) * 64;
                const unsigned short* kp = &Kg[(size_t)(nb + row) * 1536];
                kr0 = *(const uint4*)&kp[(2 * t4) * 8];
                kr1 = *(const uint4*)&kp[(2 * t4 + 1) * 8];
                const unsigned short* vp = &Vh[(size_t)row * SEQ + nb];
                vr0 = *(const uint4*)&vp[t4 * 16];
                vr1 = *(const uint4*)&vp[t4 * 16 + 8];
            }
        }

        const int kbase = kt * 64;
        const bool cur = (kbase <= qw);

        short4v pka[4], pkb[4];
        if (cur) {
            softmax_q(sa, m_a, l_a, Oa, pka);
            softmax_q(sb, m_b, l_b, Ob, pkb);
        }

        const int kn = kbase + 64;
        if (kt < ke && kn <= qw) {
            const unsigned short* Kc = &Ks3[b1][0];
            for (int nt = 0; nt < 4; nt++) {
                short8 aK0 = *(const short8*)&Kc[(nt * 16 + l16) * 64 + (quad ^ swr) * 8];
                short8 aK1 = *(const short8*)&Kc[(nt * 16 + l16) * 64 + ((quad + 4) ^ swr) * 8];
                f32x4 za = {};
                za = mfma32(aK0, bQ0a, za);
                za = mfma32(aK1, bQ1a, za);
                sa[nt] = za;
                f32x4 zb = {};
                zb = mfma32(aK0, bQ0b, zb);
                zb = mfma32(aK1, bQ1b, zb);
                sb[nt] = zb;
            }
            if (kn + 63 > qbase + wave * 32) {
                for (int nt = 0; nt < 4; nt++)
                    for (int r = 0; r < 4; r++) {
                        const int kk = kn + nt * 16 + quad * 4 + r;
                        if (kk > qa) sa[nt][r] = -INFINITY;
                        if (kk > qb) sb[nt][r] = -INFINITY;
                    }
            }
        }

        if (cur) {
            const unsigned short* Vc = &Vs3[b0][0];
            for (int dt = 0; dt < 4; dt++)
                for (int nt = 0; nt < 4; nt++) {
                    short4v av =
                        *(const short4v*)&Vc[(dt * 16 + l16) * 64 + ((4 * nt + quad) ^ l16) * 4];
                    Oa[dt] = mfma16(av, pka[nt], Oa[dt]);
                    Ob[dt] = mfma16(av, pkb[nt], Ob[dt]);
                }
        }

        b0 = b1;
    }

    // deferred cross-lane l reduction (m is quad-uniform by construction)
    l_a += __shfl_xor(l_a, 16);
    l_a += __shfl_xor(l_a, 32);
    l_b += __shfl_xor(l_b, 16);
    l_b += __shfl_xor(l_b, 32);

    const int qla = wave * 32 + l16;  // 0..127 across 4 waves (set a)
    const int qlb = qla + 16;         // set b
    if (nch == 1) {
        const float ia = 1.f / l_a, ib = 1.f / l_b;
        for (int dt = 0; dt < 4; dt++) {
            ushort4 oa, ob;
            oa.x = f2bf(Oa[dt][0] * ia);
            oa.y = f2bf(Oa[dt][1] * ia);
            oa.z = f2bf(Oa[dt][2] * ia);
            oa.w = f2bf(Oa[dt][3] * ia);
            ob.x = f2bf(Ob[dt][0] * ib);
            ob.y = f2bf(Ob[dt][1] * ib);
            ob.z = f2bf(Ob[dt][2] * ib);
            ob.w = f2bf(Ob[dt][3] * ib);
            *(ushort4*)&ctxb[(size_t)qa * EMB + h * HD + dt * 16 + quad * 4] = oa;
            *(ushort4*)&ctxb[(size_t)qb * EMB + h * HD + dt * 16 + quad * 4] = ob;
        }
    } else {
        if (ch == 0) {
            for (int dt = 0; dt < 4; dt++) {
                ushort4 oa, ob;
                oa.x = f2bf(Oa[dt][0]);
                oa.y = f2bf(Oa[dt][1]);
                oa.z = f2bf(Oa[dt][2]);
                oa.w = f2bf(Oa[dt][3]);
                ob.x = f2bf(Ob[dt][0]);
                ob.y = f2bf(Ob[dt][1]);
                ob.z = f2bf(Ob[dt][2]);
                ob.w = f2bf(Ob[dt][3]);
                *(ushort4*)&ctxb[(size_t)qa * EMB + h * HD + dt * 16 + quad * 4] = oa;
                *(ushort4*)&ctxb[(size_t)qb * EMB + h * HD + dt * 16 + quad * 4] = ob;
            }
        } else {
            const int pid = pid_of(h, i128, ch);
            for (int dt = 0; dt < 4; dt++) {
                ushort4 oa, ob;
                oa.x = f2bf(Oa[dt][0]);
                oa.y = f2bf(Oa[dt][1]);
                oa.z = f2bf(Oa[dt][2]);
                oa.w = f2bf(Oa[dt][3]);
                ob.x = f2bf(Ob[dt][0]);
                ob.y = f2bf(Ob[dt][1]);
                ob.z = f2bf(Ob[dt][2]);
                ob.w = f2bf(Ob[dt][3]);
                *(ushort4*)&Op[(size_t)pid * 8192 + qla * 64 + dt * 16 + quad * 4] = oa;
                *(ushort4*)&Op[(size_t)pid * 8192 + qlb * 64 + dt * 16 + quad * 4] = ob;
            }
        }
        if (quad == 0) {
            const int mlb = ((h * 32 + i128) * 4 + ch) * 128;
            mArr[mlb + qla] = m_a;
            lArr[mlb + qla] = l_a;
            mArr[mlb + qlb] = m_b;
            lArr[mlb + qlb] = l_b;
        }
    }
}

// ---------------------------------------------------------------- merge (i128>=10)
__global__ __launch_bounds__(256) void merge_kernel(const unsigned short* __restrict__ Op,
                                                    const float* __restrict__ mArr,
                                                    const float* __restrict__ lArr,
                                                    unsigned short* __restrict__ ctxb) {
    const int gid = blockIdx.x;  // 0..263
    const int h = gid % HEADS;
    const int i128 = 10 + gid / HEADS;
    const int nch = (i128 < 20) ? 2 : (i128 < 30) ? 3 : 4;
    const int q = threadIdx.x >> 1, d0 = (threadIdx.x & 1) * 32;
    const int mlbase = (h * 32 + i128) * 4;

    float mc[4], lc[4];
    for (int c = 0; c < nch; c++) {
        mc[c] = mArr[(mlbase + c) * 128 + q];
        lc[c] = lArr[(mlbase + c) * 128 + q];
    }
    float M = mc[0];
    for (int c = 1; c < nch; c++) M = fmaxf(M, mc[c]);
    float w[4], L = 0.f;
    for (int c = 0; c < nch; c++) {
        w[c] = __builtin_amdgcn_exp2f(mc[c] - M);
        L += w[c] * lc[c];
    }
    const float inv = 1.f / L;
    for (int c = 0; c < nch; c++) w[c] *= inv;

    unsigned short* dst = &ctxb[(size_t)(i128 * 128 + q) * EMB + h * HD + d0];
    for (int jj = 0; jj < 32; jj += 8) {
        uint4 u0 = *(const uint4*)&dst[jj];  // chunk0 (unnormalized) in place
        float f[8];
        const unsigned short* p0 = (const unsigned short*)&u0;
        for (int t = 0; t < 8; t++)
            f[t] = w[0] * __builtin_bit_cast(float, (unsigned int)p0[t] << 16);
        for (int c = 1; c < nch; c++) {
            const int pid = pid_of(h, i128, c);
            uint4 u = *(const uint4*)&Op[(size_t)pid * 8192 + q * 64 + d0 + jj];
            const unsigned short* p = (const unsigned short*)&u;
            for (int t = 0; t < 8; t++)
                f[t] += w[c] * __builtin_bit_cast(float, (unsigned int)p[t] << 16);
        }
        unsigned short o[8];
        for (int t = 0; t < 8; t++) o[t] = f2bf(f[t]);
        *(uint4*)&dst[jj] = *(uint4*)o;
    }
}

// ---------------------------------------------------------------- launch
extern "C" void kernel_launch(void* const* d_in, const int* in_sizes, int n_in,
                              void* d_out, int out_size, void* d_ws, size_t ws_size,
                              hipStream_t stream) {
    const float* x = (const float*)d_in[0];
    const float* wq = (const float*)d_in[1];
    const float* bq = (const float*)d_in[2];
    const float* wk = (const float*)d_in[3];
    const float* bk = (const float*)d_in[4];
    const float* wv = (const float*)d_in[5];
    const float* bv = (const float*)d_in[6];
    const float* wo = (const float*)d_in[7];
    const float* bo = (const float*)d_in[8];

    unsigned short* ws = (unsigned short*)d_ws;
    unsigned short* xb = ws;                          // 3,145,728 ush
    unsigned short* wqkvT = xb + SEQ * EMB;           // 1,769,472
    unsigned short* woT = wqkvT + 3 * EMB * EMB;      // 589,824
    unsigned short* QKb = woT + EMB * EMB;            // 4096*1536
    unsigned short* Vtb = QKb + (size_t)SEQ * 1536;   // 3,145,728
    unsigned short* ctxb = Vtb + HEADS * SEQ * HD;    // 3,145,728
    // attn-phase scratch aliases xb+wqkvT (dead after gemm_qkv):
    // Op 432*8192 = 3,538,944 ush; mArr/lArr 196,608 f32 each -> ends 4,325,376
    unsigned short* Op = xb;
    float* mArr = (float*)(ws + 3538944);
    float* lArr = mArr + 196608;

    convert_all<<<dim3(3072 + 576), 256, 0, stream>>>(x, wq, wk, wv, wo, xb, wqkvT, woT);
    gemm_qkv<<<dim3(SEQ / 64, 3 * EMB / 128), 256, 0, stream>>>(
        xb, wqkvT, bq, bk, bv, QKb, Vtb);
    attn_kernel<<<dim3(12 * 68), 256, 0, stream>>>(QKb, Vtb, ctxb, Op, mArr, lArr);
    merge_kernel<<<dim3(264), 256, 0, stream>>>(Op, mArr, lArr, ctxb);
    gemm_out<<<dim3(SEQ / 64, EMB / 64), 256, 0, stream>>>(ctxb, woT, bo, (float*)d_out);
}